// Round 3
// baseline (665.289 us; speedup 1.0000x reference)
//
#include <hip/hip_runtime.h>

typedef short short8 __attribute__((ext_vector_type(8)));
typedef float f32x4 __attribute__((ext_vector_type(4)));

#define EPSF 1e-5f
#define THRF 0.2987f

constexpr int N_ = 64, C_ = 128;
constexpr int PLANE = 4096;                         // 64*64
constexpr size_t TENSOR = (size_t)N_ * C_ * PLANE;  // 33554432
constexpr int NHW = N_ * PLANE;                     // 262144

__device__ __forceinline__ unsigned short f2bf(float f) {
    unsigned u = __float_as_uint(f);
    u += 0x7fffu + ((u >> 16) & 1u);  // RNE
    return (unsigned short)(u >> 16);
}

// ---------- weight prep: [co][ci][3][3] fp32 -> [tap][co][ci] bf16 ----------
__global__ __launch_bounds__(256) void prep_w_k(const float* __restrict__ w1,
                                                const float* __restrict__ w2,
                                                unsigned short* __restrict__ Wt1,
                                                unsigned short* __restrict__ Wt2) {
    int idx = blockIdx.x * 256 + threadIdx.x;  // 0..294911
    const int sel = idx >= 147456;
    const float* src = sel ? w2 : w1;
    unsigned short* dst = sel ? Wt2 : Wt1;
    const int r = idx - sel * 147456;
    const int tap = r >> 14;
    const int rem = r & 16383;
    const int co = rem >> 7, ci = rem & 127;
    dst[r] = f2bf(src[(co * 128 + ci) * 9 + tap]);
}

// ---------- NCHW fp32 -> NHWC bf16 transpose (optionally fused BN+ReLU+mask) ----------
__global__ __launch_bounds__(256) void to_nhwc_k(const float* __restrict__ src,
                                                 const float* __restrict__ st,
                                                 const float* __restrict__ maskb,
                                                 unsigned short* __restrict__ dst,
                                                 int apply) {
    __shared__ __align__(16) unsigned short tl[64 * 40];
    const int b = blockIdx.x;
    const int c0 = (b & 3) * 32;
    const int h  = (b >> 2) & 63;
    const int n  = b >> 8;
    const int t  = threadIdx.x;
    for (int i = t; i < 512; i += 256) {
        const int cl = i >> 4;
        const int c  = c0 + cl;
        const int w4 = (i & 15) * 4;
        float4 v = *(const float4*)&src[(size_t)(n * 128 + c) * 4096 + h * 64 + w4];
        if (apply) {
            const float sc = st[c], sh = st[128 + c];
            const float m  = maskb[n * 128 + c];
            v.x = fmaxf(fmaf(v.x, sc, sh), 0.f) * m;
            v.y = fmaxf(fmaf(v.y, sc, sh), 0.f) * m;
            v.z = fmaxf(fmaf(v.z, sc, sh), 0.f) * m;
            v.w = fmaxf(fmaf(v.w, sc, sh), 0.f) * m;
        }
        tl[(w4 + 0) * 40 + cl] = f2bf(v.x);
        tl[(w4 + 1) * 40 + cl] = f2bf(v.y);
        tl[(w4 + 2) * 40 + cl] = f2bf(v.z);
        tl[(w4 + 3) * 40 + cl] = f2bf(v.w);
    }
    __syncthreads();
    const int w = t >> 2, cs = t & 3;
    short8 v = *(const short8*)&tl[w * 40 + cs * 8];
    *(short8*)&dst[((size_t)n * 4096 + h * 64 + w) * 128 + c0 + cs * 8] = v;
}

// ---------- conv3x3 via MFMA implicit GEMM + fused BN-stat partials ----------
// inT: NHWC bf16; Wt: [9][128 co][128 ci] bf16; out: NCHW fp32; part: [block][256].
// grid = N * 32 = 2048 blocks, 256 thr. Block: 128 co x (2 rows x 64 w).
// Per ci-slice (32): stage input tile + ALL 9 taps of weights, then 144 MFMA
// between one barrier pair (was 72 barriers/block, now 9).
__global__ __launch_bounds__(256) void conv_mfma_k(const unsigned short* __restrict__ inT,
                                                   const unsigned short* __restrict__ Wt,
                                                   float* __restrict__ out,
                                                   float* __restrict__ part) {
    __shared__ __align__(16) short sIn[264 * 40];      // 21,120 B
    __shared__ __align__(16) short sW[9 * 128 * 40];   // 92,160 B
    __shared__ float fS[256], fQ[256];                 // epilogue scratch

    const int b  = blockIdx.x;
    const int h0 = (b & 31) * 2;
    const int n  = b >> 5;
    const int tid  = threadIdx.x;
    const int lane = tid & 63;
    const int wid  = tid >> 6;
    const int co_base = (wid >> 1) * 64;
    const int px_base = (wid & 1) * 64;
    const int lr = lane & 15;
    const int lg = lane >> 4;

    f32x4 acc[4][4];
#pragma unroll
    for (int i = 0; i < 4; ++i)
#pragma unroll
        for (int j = 0; j < 4; ++j) acc[i][j] = (f32x4){0.f, 0.f, 0.f, 0.f};

    const size_t inBase = (size_t)n * 4096 * 128;

    for (int cs = 0; cs < 4; ++cs) {
        const int ci0 = cs * 32;
        if (cs) __syncthreads();  // protect LDS from overwrite while readers active
        // stage input tile: 264 spatial x 32 ci
        for (int i = tid; i < 1056; i += 256) {
            const int seg = i & 3;
            const int sp  = i >> 2;
            const int r   = sp / 66;
            const int c   = sp - r * 66;
            const int gh  = h0 + r - 1;
            const int gw  = c - 1;
            short8 v = {0, 0, 0, 0, 0, 0, 0, 0};
            if ((unsigned)gh < 64u && (unsigned)gw < 64u)
                v = *(const short8*)&inT[inBase + ((size_t)gh * 64 + gw) * 128 + ci0 + seg * 8];
            *(short8*)&sIn[sp * 40 + seg * 8] = v;
        }
        // stage ALL 9 taps of weights for this ci-slice: 4608 x 16B
        for (int i = tid; i < 4608; i += 256) {
            const int tap = i >> 9;
            const int rem = i & 511;
            const int co  = rem >> 2;
            const int seg = rem & 3;
            *(short8*)&sW[(tap * 128 + co) * 40 + seg * 8] =
                *(const short8*)&Wt[((size_t)tap * 128 + co) * 128 + ci0 + seg * 8];
        }
        __syncthreads();
#pragma unroll
        for (int tap = 0; tap < 9; ++tap) {
            const int dr = tap / 3, dc = tap - dr * 3;
            short8 af[4], bf[4];
#pragma unroll
            for (int i = 0; i < 4; ++i)
                af[i] = *(const short8*)&sW[(tap * 128 + co_base + i * 16 + lr) * 40 + lg * 8];
#pragma unroll
            for (int j = 0; j < 4; ++j) {
                const int px = px_base + j * 16 + lr;
                const int r = px >> 6, c = px & 63;
                bf[j] = *(const short8*)&sIn[((r + dr) * 66 + c + dc) * 40 + lg * 8];
            }
#pragma unroll
            for (int i = 0; i < 4; ++i)
#pragma unroll
                for (int j = 0; j < 4; ++j)
                    acc[i][j] = __builtin_amdgcn_mfma_f32_16x16x32_bf16(af[i], bf[j], acc[i][j], 0, 0, 0);
        }
    }

    // ---- epilogue 1: per-(block, co) BN partials (sum, sumsq over this block's 128 px)
    // D layout: col(px)=lr, row(co)=lg*4+q.
#pragma unroll
    for (int i = 0; i < 4; ++i)
#pragma unroll
        for (int q = 0; q < 4; ++q) {
            float v = acc[i][0][q] + acc[i][1][q] + acc[i][2][q] + acc[i][3][q];
            float w = acc[i][0][q] * acc[i][0][q] + acc[i][1][q] * acc[i][1][q]
                    + acc[i][2][q] * acc[i][2][q] + acc[i][3][q] * acc[i][3][q];
#pragma unroll
            for (int m = 1; m < 16; m <<= 1) {
                v += __shfl_xor(v, m);
                w += __shfl_xor(w, m);
            }
            if (lr == 0) {
                const int colocal = i * 16 + lg * 4 + q;
                fS[wid * 64 + colocal] = v;
                fQ[wid * 64 + colocal] = w;
            }
        }
    __syncthreads();
    if (tid < 128) {
        const int grp = tid >> 6, cl = tid & 63;
        part[(size_t)b * 256 + tid]       = fS[(grp * 2) * 64 + cl] + fS[(grp * 2 + 1) * 64 + cl];
        part[(size_t)b * 256 + 128 + tid] = fQ[(grp * 2) * 64 + cl] + fQ[(grp * 2 + 1) * 64 + cl];
    }

    // ---- epilogue 2: write NCHW fp32
    const size_t outN = (size_t)n * 128 * 4096;
#pragma unroll
    for (int i = 0; i < 4; ++i) {
        const int cob = co_base + i * 16 + lg * 4;
#pragma unroll
        for (int q = 0; q < 4; ++q) {
            float* op = out + outN + (size_t)(cob + q) * 4096 + h0 * 64 + px_base + lr;
#pragma unroll
            for (int j = 0; j < 4; ++j) op[j * 16] = acc[i][j][q];
        }
    }
}

// ---------- fold per-block partials -> per-channel scale/shift ----------
// grid = 128 (one block per channel), 256 threads
__global__ __launch_bounds__(256) void bn_finalize_k(const float* __restrict__ part,
                                                     const float* __restrict__ gamma,
                                                     const float* __restrict__ beta,
                                                     float* __restrict__ st) {
    const int c = blockIdx.x;
    float s = 0.f, q = 0.f;
    for (int b = threadIdx.x; b < 2048; b += 256) {
        s += part[(size_t)b * 256 + c];
        q += part[(size_t)b * 256 + 128 + c];
    }
    __shared__ float rs[256], rq[256];
    rs[threadIdx.x] = s; rq[threadIdx.x] = q;
    __syncthreads();
    for (int o = 128; o > 0; o >>= 1) {
        if (threadIdx.x < o) {
            rs[threadIdx.x] += rs[threadIdx.x + o];
            rq[threadIdx.x] += rq[threadIdx.x + o];
        }
        __syncthreads();
    }
    if (threadIdx.x == 0) {
        const float inv  = 1.f / (float)NHW;
        const float mean = rs[0] * inv;
        const float var  = rq[0] * inv - mean * mean;
        const float sc   = gamma[c] * rsqrtf(var + EPSF);
        st[c]       = sc;
        st[C_ + c]  = fmaf(-mean, sc, beta[c]);
    }
}

// ---------- per-(n,c) plane mean of relu(bn(y)) -> mask 0/1 ----------
__global__ __launch_bounds__(256) void mask_means_k(const float* __restrict__ y,
                                                    const float* __restrict__ st,
                                                    float* __restrict__ maskb) {
    const int p = blockIdx.x;  // n*128 + c
    const int c = p & 127;
    const float sc = st[c], sh = st[128 + c];
    const float4* src = (const float4*)(y + (size_t)p * PLANE);
    float s = 0.f;
    for (int j = threadIdx.x; j < 1024; j += 256) {
        float4 v = src[j];
        s += fmaxf(fmaf(v.x, sc, sh), 0.f) + fmaxf(fmaf(v.y, sc, sh), 0.f)
           + fmaxf(fmaf(v.z, sc, sh), 0.f) + fmaxf(fmaf(v.w, sc, sh), 0.f);
    }
    __shared__ float rs[256];
    rs[threadIdx.x] = s;
    __syncthreads();
    for (int o = 128; o > 0; o >>= 1) {
        if (threadIdx.x < o) rs[threadIdx.x] += rs[threadIdx.x + o];
        __syncthreads();
    }
    if (threadIdx.x == 0) maskb[p] = (rs[0] * (1.f / 4096.f) >= THRF) ? 1.f : 0.f;
}

// ---------- final: relu(bn2(y3) + x), NCHW ----------
__global__ __launch_bounds__(256) void final_k(const float* __restrict__ y3,
                                               const float* __restrict__ x,
                                               const float* __restrict__ st,
                                               float* __restrict__ out) {
    const size_t total4 = TENSOR / 4;
    for (size_t i = (size_t)blockIdx.x * 256 + threadIdx.x; i < total4;
         i += (size_t)gridDim.x * 256) {
        const int c = (int)((i >> 10) & (C_ - 1));
        const float sc = st[c], sh = st[C_ + c];
        float4 a = ((const float4*)y3)[i];
        float4 b = ((const float4*)x)[i];
        a.x = fmaxf(fmaf(a.x, sc, sh) + b.x, 0.f);
        a.y = fmaxf(fmaf(a.y, sc, sh) + b.y, 0.f);
        a.z = fmaxf(fmaf(a.z, sc, sh) + b.z, 0.f);
        a.w = fmaxf(fmaf(a.w, sc, sh) + b.w, 0.f);
        ((float4*)out)[i] = a;
    }
}

extern "C" void kernel_launch(void* const* d_in, const int* in_sizes, int n_in,
                              void* d_out, int out_size, void* d_ws, size_t ws_size,
                              hipStream_t stream) {
    const float* x  = (const float*)d_in[0];
    const float* w1 = (const float*)d_in[1];
    const float* g1 = (const float*)d_in[2];
    const float* b1 = (const float*)d_in[3];
    const float* w2 = (const float*)d_in[4];
    const float* g2 = (const float*)d_in[5];
    const float* b2 = (const float*)d_in[6];
    float* out = (float*)d_out;

    char* wsb = (char*)d_ws;
    unsigned short* io  = (unsigned short*)wsb;                       // 67,108,864 B (NHWC bf16)
    unsigned short* Wt1 = (unsigned short*)(wsb + (size_t)67108864);  // 294,912 B
    unsigned short* Wt2 = Wt1 + 147456;                               // 294,912 B
    float* part  = (float*)(wsb + (size_t)67108864 + 589824);         // 2048*256*4 = 2 MB
    float* st1   = part + 2048 * 256;
    float* st2   = st1 + 256;
    float* maskb = st2 + 256;                                         // 8192 floats

    prep_w_k<<<1152, 256, 0, stream>>>(w1, w2, Wt1, Wt2);
    // x -> NHWC bf16
    to_nhwc_k<<<16384, 256, 0, stream>>>(x, st1, maskb, io, 0);
    // conv1: io -> d_out (y1, NCHW fp32) + BN1 partials
    conv_mfma_k<<<2048, 256, 0, stream>>>(io, Wt1, out, part);
    bn_finalize_k<<<128, 256, 0, stream>>>(part, g1, b1, st1);
    // per-(n,c) means -> mask
    mask_means_k<<<8192, 256, 0, stream>>>(out, st1, maskb);
    // bn1+relu+mask, y1 NCHW -> NHWC bf16 (overwrites io)
    to_nhwc_k<<<16384, 256, 0, stream>>>(out, st1, maskb, io, 1);
    // conv2: io -> d_out (y3) + BN2 partials
    conv_mfma_k<<<2048, 256, 0, stream>>>(io, Wt2, out, part);
    bn_finalize_k<<<128, 256, 0, stream>>>(part, g2, b2, st2);
    // relu(bn2(y3)+x) in-place on d_out
    final_k<<<8192, 256, 0, stream>>>(out, x, st2, out);
}

// Round 4
// 539.174 us; speedup vs baseline: 1.2339x; 1.2339x over previous
//
#include <hip/hip_runtime.h>

typedef short short8 __attribute__((ext_vector_type(8)));
typedef float f32x4 __attribute__((ext_vector_type(4)));

#define EPSF 1e-5f
#define THRF 0.2987f

constexpr int N_ = 64, C_ = 128;
constexpr int PLANE = 4096;                         // 64*64
constexpr size_t TENSOR = (size_t)N_ * C_ * PLANE;  // 33554432
constexpr int NHW = N_ * PLANE;                     // 262144

__device__ __forceinline__ unsigned short f2bf(float f) {
    unsigned u = __float_as_uint(f);
    u += 0x7fffu + ((u >> 16) & 1u);  // RNE
    return (unsigned short)(u >> 16);
}

// ---------- weight prep: [co][ci][3][3] fp32 -> [tap][co][ci] bf16 ----------
__global__ __launch_bounds__(256) void prep_w_k(const float* __restrict__ w1,
                                                const float* __restrict__ w2,
                                                unsigned short* __restrict__ Wt1,
                                                unsigned short* __restrict__ Wt2) {
    int idx = blockIdx.x * 256 + threadIdx.x;  // 0..294911
    const int sel = idx >= 147456;
    const float* src = sel ? w2 : w1;
    unsigned short* dst = sel ? Wt2 : Wt1;
    const int r = idx - sel * 147456;
    const int tap = r >> 14;
    const int rem = r & 16383;
    const int co = rem >> 7, ci = rem & 127;
    dst[r] = f2bf(src[(co * 128 + ci) * 9 + tap]);
}

// ---------- NCHW fp32 -> NHWC bf16 transpose (optionally fused BN+ReLU+mask) ----------
__global__ __launch_bounds__(256) void to_nhwc_k(const float* __restrict__ src,
                                                 const float* __restrict__ st,
                                                 const float* __restrict__ maskb,
                                                 unsigned short* __restrict__ dst,
                                                 int apply) {
    __shared__ __align__(16) unsigned short tl[64 * 40];
    const int b = blockIdx.x;
    const int c0 = (b & 3) * 32;
    const int h  = (b >> 2) & 63;
    const int n  = b >> 8;
    const int t  = threadIdx.x;
    for (int i = t; i < 512; i += 256) {
        const int cl = i >> 4;
        const int c  = c0 + cl;
        const int w4 = (i & 15) * 4;
        float4 v = *(const float4*)&src[(size_t)(n * 128 + c) * 4096 + h * 64 + w4];
        if (apply) {
            const float sc = st[c], sh = st[128 + c];
            const float m  = maskb[n * 128 + c];
            v.x = fmaxf(fmaf(v.x, sc, sh), 0.f) * m;
            v.y = fmaxf(fmaf(v.y, sc, sh), 0.f) * m;
            v.z = fmaxf(fmaf(v.z, sc, sh), 0.f) * m;
            v.w = fmaxf(fmaf(v.w, sc, sh), 0.f) * m;
        }
        tl[(w4 + 0) * 40 + cl] = f2bf(v.x);
        tl[(w4 + 1) * 40 + cl] = f2bf(v.y);
        tl[(w4 + 2) * 40 + cl] = f2bf(v.z);
        tl[(w4 + 3) * 40 + cl] = f2bf(v.w);
    }
    __syncthreads();
    const int w = t >> 2, cs = t & 3;
    short8 v = *(const short8*)&tl[w * 40 + cs * 8];
    *(short8*)&dst[((size_t)n * 4096 + h * 64 + w) * 128 + c0 + cs * 8] = v;
}

// ---------- conv3x3 via MFMA implicit GEMM + fused BN-stat partials ----------
// inT: NHWC bf16; Wt: [9][128 co][128 ci] bf16 (L2-resident, read direct to regs);
// out: NCHW fp32; part: [block][256].
// grid = N * 32 = 2048 blocks, 256 thr. Block: 128 co x (2 rows x 64 w).
// LDS holds ONLY the input tile (21 KB) -> several blocks/CU. 2 barriers per
// ci-slice; 144 MFMA between barrier pairs; weights stream from L2.
__global__ __launch_bounds__(256) void conv_mfma_k(const unsigned short* __restrict__ inT,
                                                   const unsigned short* __restrict__ Wt,
                                                   float* __restrict__ out,
                                                   float* __restrict__ part) {
    __shared__ __align__(16) short sIn[264 * 40];  // 21,120 B
    __shared__ float fS[256], fQ[256];

    const int b  = blockIdx.x;
    const int h0 = (b & 31) * 2;
    const int n  = b >> 5;
    const int tid  = threadIdx.x;
    const int lane = tid & 63;
    const int wid  = tid >> 6;
    const int co_base = (wid >> 1) * 64;
    const int px_base = (wid & 1) * 64;
    const int lr = lane & 15;
    const int lg = lane >> 4;

    f32x4 acc[4][4];
#pragma unroll
    for (int i = 0; i < 4; ++i)
#pragma unroll
        for (int j = 0; j < 4; ++j) acc[i][j] = (f32x4){0.f, 0.f, 0.f, 0.f};

    const size_t inBase = (size_t)n * 4096 * 128;
    // per-lane weight base: row = co_base + i*16 + lr, k-offset = lg*8
    const unsigned short* wLane = Wt + (size_t)(co_base + lr) * 128 + lg * 8;

    for (int cs = 0; cs < 4; ++cs) {
        const int ci0 = cs * 32;
        if (cs) __syncthreads();
        // stage input tile: 264 spatial x 32 ci
        for (int i = tid; i < 1056; i += 256) {
            const int seg = i & 3;
            const int sp  = i >> 2;
            const int r   = sp / 66;
            const int c   = sp - r * 66;
            const int gh  = h0 + r - 1;
            const int gw  = c - 1;
            short8 v = {0, 0, 0, 0, 0, 0, 0, 0};
            if ((unsigned)gh < 64u && (unsigned)gw < 64u)
                v = *(const short8*)&inT[inBase + ((size_t)gh * 64 + gw) * 128 + ci0 + seg * 8];
            *(short8*)&sIn[sp * 40 + seg * 8] = v;
        }
        __syncthreads();
#pragma unroll
        for (int tap = 0; tap < 9; ++tap) {
            const int dr = tap / 3, dc = tap - dr * 3;
            short8 af[4], bf[4];
#pragma unroll
            for (int i = 0; i < 4; ++i)
                af[i] = *(const short8*)&wLane[((size_t)tap * 128 + i * 16) * 128 + ci0];
#pragma unroll
            for (int j = 0; j < 4; ++j) {
                const int px = px_base + j * 16 + lr;
                const int r = px >> 6, c = px & 63;
                bf[j] = *(const short8*)&sIn[((r + dr) * 66 + c + dc) * 40 + lg * 8];
            }
#pragma unroll
            for (int i = 0; i < 4; ++i)
#pragma unroll
                for (int j = 0; j < 4; ++j)
                    acc[i][j] = __builtin_amdgcn_mfma_f32_16x16x32_bf16(af[i], bf[j], acc[i][j], 0, 0, 0);
        }
    }

    // ---- epilogue 1: per-(block, co) BN partials (sum, sumsq over 128 px)
#pragma unroll
    for (int i = 0; i < 4; ++i)
#pragma unroll
        for (int q = 0; q < 4; ++q) {
            float v = acc[i][0][q] + acc[i][1][q] + acc[i][2][q] + acc[i][3][q];
            float w = acc[i][0][q] * acc[i][0][q] + acc[i][1][q] * acc[i][1][q]
                    + acc[i][2][q] * acc[i][2][q] + acc[i][3][q] * acc[i][3][q];
#pragma unroll
            for (int m = 1; m < 16; m <<= 1) {
                v += __shfl_xor(v, m);
                w += __shfl_xor(w, m);
            }
            if (lr == 0) {
                const int colocal = i * 16 + lg * 4 + q;
                fS[wid * 64 + colocal] = v;
                fQ[wid * 64 + colocal] = w;
            }
        }
    __syncthreads();
    if (tid < 128) {
        const int grp = tid >> 6, cl = tid & 63;
        part[(size_t)b * 256 + tid]       = fS[(grp * 2) * 64 + cl] + fS[(grp * 2 + 1) * 64 + cl];
        part[(size_t)b * 256 + 128 + tid] = fQ[(grp * 2) * 64 + cl] + fQ[(grp * 2 + 1) * 64 + cl];
    }

    // ---- epilogue 2: write NCHW fp32 (D: col(px)=lr, row(co)=lg*4+q)
    const size_t outN = (size_t)n * 128 * 4096;
#pragma unroll
    for (int i = 0; i < 4; ++i) {
        const int cob = co_base + i * 16 + lg * 4;
#pragma unroll
        for (int q = 0; q < 4; ++q) {
            float* op = out + outN + (size_t)(cob + q) * 4096 + h0 * 64 + px_base + lr;
#pragma unroll
            for (int j = 0; j < 4; ++j) op[j * 16] = acc[i][j][q];
        }
    }
}

// ---------- fold per-block partials -> per-channel scale/shift ----------
__global__ __launch_bounds__(256) void bn_finalize_k(const float* __restrict__ part,
                                                     const float* __restrict__ gamma,
                                                     const float* __restrict__ beta,
                                                     float* __restrict__ st) {
    const int c = blockIdx.x;
    float s = 0.f, q = 0.f;
    for (int b = threadIdx.x; b < 2048; b += 256) {
        s += part[(size_t)b * 256 + c];
        q += part[(size_t)b * 256 + 128 + c];
    }
    __shared__ float rs[256], rq[256];
    rs[threadIdx.x] = s; rq[threadIdx.x] = q;
    __syncthreads();
    for (int o = 128; o > 0; o >>= 1) {
        if (threadIdx.x < o) {
            rs[threadIdx.x] += rs[threadIdx.x + o];
            rq[threadIdx.x] += rq[threadIdx.x + o];
        }
        __syncthreads();
    }
    if (threadIdx.x == 0) {
        const float inv  = 1.f / (float)NHW;
        const float mean = rs[0] * inv;
        const float var  = rq[0] * inv - mean * mean;
        const float sc   = gamma[c] * rsqrtf(var + EPSF);
        st[c]       = sc;
        st[C_ + c]  = fmaf(-mean, sc, beta[c]);
    }
}

// ---------- per-(n,c) plane mean of relu(bn(y)) -> mask 0/1 ----------
__global__ __launch_bounds__(256) void mask_means_k(const float* __restrict__ y,
                                                    const float* __restrict__ st,
                                                    float* __restrict__ maskb) {
    const int p = blockIdx.x;  // n*128 + c
    const int c = p & 127;
    const float sc = st[c], sh = st[128 + c];
    const float4* src = (const float4*)(y + (size_t)p * PLANE);
    float s = 0.f;
    for (int j = threadIdx.x; j < 1024; j += 256) {
        float4 v = src[j];
        s += fmaxf(fmaf(v.x, sc, sh), 0.f) + fmaxf(fmaf(v.y, sc, sh), 0.f)
           + fmaxf(fmaf(v.z, sc, sh), 0.f) + fmaxf(fmaf(v.w, sc, sh), 0.f);
    }
    __shared__ float rs[256];
    rs[threadIdx.x] = s;
    __syncthreads();
    for (int o = 128; o > 0; o >>= 1) {
        if (threadIdx.x < o) rs[threadIdx.x] += rs[threadIdx.x + o];
        __syncthreads();
    }
    if (threadIdx.x == 0) maskb[p] = (rs[0] * (1.f / 4096.f) >= THRF) ? 1.f : 0.f;
}

// ---------- final: relu(bn2(y3) + x), NCHW ----------
__global__ __launch_bounds__(256) void final_k(const float* __restrict__ y3,
                                               const float* __restrict__ x,
                                               const float* __restrict__ st,
                                               float* __restrict__ out) {
    const size_t total4 = TENSOR / 4;
    for (size_t i = (size_t)blockIdx.x * 256 + threadIdx.x; i < total4;
         i += (size_t)gridDim.x * 256) {
        const int c = (int)((i >> 10) & (C_ - 1));
        const float sc = st[c], sh = st[C_ + c];
        float4 a = ((const float4*)y3)[i];
        float4 b = ((const float4*)x)[i];
        a.x = fmaxf(fmaf(a.x, sc, sh) + b.x, 0.f);
        a.y = fmaxf(fmaf(a.y, sc, sh) + b.y, 0.f);
        a.z = fmaxf(fmaf(a.z, sc, sh) + b.z, 0.f);
        a.w = fmaxf(fmaf(a.w, sc, sh) + b.w, 0.f);
        ((float4*)out)[i] = a;
    }
}

extern "C" void kernel_launch(void* const* d_in, const int* in_sizes, int n_in,
                              void* d_out, int out_size, void* d_ws, size_t ws_size,
                              hipStream_t stream) {
    const float* x  = (const float*)d_in[0];
    const float* w1 = (const float*)d_in[1];
    const float* g1 = (const float*)d_in[2];
    const float* b1 = (const float*)d_in[3];
    const float* w2 = (const float*)d_in[4];
    const float* g2 = (const float*)d_in[5];
    const float* b2 = (const float*)d_in[6];
    float* out = (float*)d_out;

    char* wsb = (char*)d_ws;
    unsigned short* io  = (unsigned short*)wsb;                       // 67,108,864 B (NHWC bf16)
    unsigned short* Wt1 = (unsigned short*)(wsb + (size_t)67108864);  // 294,912 B
    unsigned short* Wt2 = Wt1 + 147456;                               // 294,912 B
    float* part  = (float*)(wsb + (size_t)67108864 + 589824);         // 2 MB
    float* st1   = part + 2048 * 256;
    float* st2   = st1 + 256;
    float* maskb = st2 + 256;

    prep_w_k<<<1152, 256, 0, stream>>>(w1, w2, Wt1, Wt2);
    to_nhwc_k<<<16384, 256, 0, stream>>>(x, st1, maskb, io, 0);
    conv_mfma_k<<<2048, 256, 0, stream>>>(io, Wt1, out, part);
    bn_finalize_k<<<128, 256, 0, stream>>>(part, g1, b1, st1);
    mask_means_k<<<8192, 256, 0, stream>>>(out, st1, maskb);
    to_nhwc_k<<<16384, 256, 0, stream>>>(out, st1, maskb, io, 1);
    conv_mfma_k<<<2048, 256, 0, stream>>>(io, Wt2, out, part);
    bn_finalize_k<<<128, 256, 0, stream>>>(part, g2, b2, st2);
    final_k<<<8192, 256, 0, stream>>>(out, x, st2, out);
}

// Round 5
// 519.613 us; speedup vs baseline: 1.2804x; 1.0376x over previous
//
#include <hip/hip_runtime.h>

typedef short short8 __attribute__((ext_vector_type(8)));
typedef short short4v __attribute__((ext_vector_type(4)));
typedef float f32x4 __attribute__((ext_vector_type(4)));

#define EPSF 1e-5f
#define THRF 0.2987f

constexpr int N_ = 64, C_ = 128;
constexpr int PLANE = 4096;
constexpr size_t TENSOR = (size_t)N_ * C_ * PLANE;  // 33554432
constexpr int NHW = N_ * PLANE;                     // 262144

__device__ __forceinline__ unsigned short f2bf(float f) {
    unsigned u = __float_as_uint(f);
    u += 0x7fffu + ((u >> 16) & 1u);  // RNE
    return (unsigned short)(u >> 16);
}
__device__ __forceinline__ float bf2f(unsigned short h) {
    return __uint_as_float((unsigned)h << 16);
}

// ---------- weight prep: [co][ci][3][3] fp32 -> [tap][co][ci] bf16 ----------
__global__ __launch_bounds__(256) void prep_w_k(const float* __restrict__ w1,
                                                const float* __restrict__ w2,
                                                unsigned short* __restrict__ Wt1,
                                                unsigned short* __restrict__ Wt2) {
    int idx = blockIdx.x * 256 + threadIdx.x;  // 0..294911
    const int sel = idx >= 147456;
    const float* src = sel ? w2 : w1;
    unsigned short* dst = sel ? Wt2 : Wt1;
    const int r = idx - sel * 147456;
    const int tap = r >> 14;
    const int rem = r & 16383;
    const int co = rem >> 7, ci = rem & 127;
    dst[r] = f2bf(src[(co * 128 + ci) * 9 + tap]);
}

// ---------- NCHW fp32 -> NHWC bf16 transpose (x only) ----------
__global__ __launch_bounds__(256) void to_nhwc_k(const float* __restrict__ src,
                                                 unsigned short* __restrict__ dst) {
    __shared__ __align__(16) unsigned short tl[64 * 40];
    const int b = blockIdx.x;
    const int c0 = (b & 3) * 32;
    const int h  = (b >> 2) & 63;
    const int n  = b >> 8;
    const int t  = threadIdx.x;
    for (int i = t; i < 512; i += 256) {
        const int cl = i >> 4;
        const int c  = c0 + cl;
        const int w4 = (i & 15) * 4;
        float4 v = *(const float4*)&src[(size_t)(n * 128 + c) * 4096 + h * 64 + w4];
        tl[(w4 + 0) * 40 + cl] = f2bf(v.x);
        tl[(w4 + 1) * 40 + cl] = f2bf(v.y);
        tl[(w4 + 2) * 40 + cl] = f2bf(v.z);
        tl[(w4 + 3) * 40 + cl] = f2bf(v.w);
    }
    __syncthreads();
    const int w = t >> 2, cs = t & 3;
    short8 v = *(const short8*)&tl[w * 40 + cs * 8];
    *(short8*)&dst[((size_t)n * 4096 + h * 64 + w) * 128 + c0 + cs * 8] = v;
}

// ---------- conv3x3 MFMA implicit GEMM, fused BN partials ----------
// STAGE 1: in = io (x, bf16 NHWC), out = y1 bf16 NHWC.
// STAGE 2: in = y1; staging applies relu(y*ms+mh) (BN1+relu+mask); out = y3 fp32 NCHW.
// grid 2048 = n(64) x h0(32); block 256 thr = 4 waves; tile 128co x (2h x 64w).
// ci in 2 halves of 64; LDS 35.9KB; 4 barrier pairs; weights streamed from L2.
template <int STAGE>
__global__ __launch_bounds__(256, 3) void conv_mfma_k(
    const unsigned short* __restrict__ inT, const unsigned short* __restrict__ Wt,
    const float* __restrict__ msA, const float* __restrict__ mhA,
    unsigned short* __restrict__ outB, float* __restrict__ outF,
    float* __restrict__ part) {
    __shared__ __align__(16) short sIn[264 * 68];  // [4r x 66c][64ci pad68] = 35,904 B
    __shared__ float fS[256], fQ[256];

    const int b  = blockIdx.x;
    const int h0 = (b & 31) * 2;
    const int n  = b >> 5;
    const int tid  = threadIdx.x;
    const int lane = tid & 63;
    const int wid  = tid >> 6;
    const int co_base = (wid >> 1) * 64;
    const int px_base = (wid & 1) * 64;
    const int lr = lane & 15;
    const int lg = lane >> 4;

    f32x4 acc[4][4];
#pragma unroll
    for (int i = 0; i < 4; ++i)
#pragma unroll
        for (int j = 0; j < 4; ++j) acc[i][j] = (f32x4){0.f, 0.f, 0.f, 0.f};

    const size_t inBase = (size_t)n * 4096 * 128;
    const int nc = n * 128;

    for (int half = 0; half < 2; ++half) {
        const int ci0 = half * 64;
        if (half) __syncthreads();
        // stage input tile: 264 spatial x 64 ci (8 segs of 8)
        for (int i = tid; i < 2112; i += 256) {
            const int seg = i & 7;
            const int sp  = i >> 3;
            const int r   = sp / 66;
            const int c   = sp - r * 66;
            const int gh  = h0 + r - 1;
            const int gw  = c - 1;
            short8 v = {0, 0, 0, 0, 0, 0, 0, 0};
            if ((unsigned)gh < 64u && (unsigned)gw < 64u) {
                v = *(const short8*)&inT[inBase + ((size_t)gh * 64 + gw) * 128 + ci0 + seg * 8];
                if (STAGE == 2) {
                    const int cb = ci0 + seg * 8;
                    const float4 m0 = *(const float4*)&msA[nc + cb];
                    const float4 m1 = *(const float4*)&msA[nc + cb + 4];
                    const float4 a0 = *(const float4*)&mhA[nc + cb];
                    const float4 a1 = *(const float4*)&mhA[nc + cb + 4];
                    short8 w;
                    w[0] = (short)f2bf(fmaxf(fmaf(bf2f((unsigned short)v[0]), m0.x, a0.x), 0.f));
                    w[1] = (short)f2bf(fmaxf(fmaf(bf2f((unsigned short)v[1]), m0.y, a0.y), 0.f));
                    w[2] = (short)f2bf(fmaxf(fmaf(bf2f((unsigned short)v[2]), m0.z, a0.z), 0.f));
                    w[3] = (short)f2bf(fmaxf(fmaf(bf2f((unsigned short)v[3]), m0.w, a0.w), 0.f));
                    w[4] = (short)f2bf(fmaxf(fmaf(bf2f((unsigned short)v[4]), m1.x, a1.x), 0.f));
                    w[5] = (short)f2bf(fmaxf(fmaf(bf2f((unsigned short)v[5]), m1.y, a1.y), 0.f));
                    w[6] = (short)f2bf(fmaxf(fmaf(bf2f((unsigned short)v[6]), m1.z, a1.z), 0.f));
                    w[7] = (short)f2bf(fmaxf(fmaf(bf2f((unsigned short)v[7]), m1.w, a1.w), 0.f));
                    v = w;
                }
            }
            *(short8*)&sIn[sp * 68 + seg * 8] = v;
        }
        __syncthreads();
#pragma unroll
        for (int tap = 0; tap < 9; ++tap) {
            const int dr = tap / 3, dc = tap - dr * 3;
            short8 af[4][2], bfv[2][4];
#pragma unroll
            for (int i = 0; i < 4; ++i)
#pragma unroll
                for (int cs = 0; cs < 2; ++cs)
                    af[i][cs] = *(const short8*)&Wt[((size_t)tap * 128 + co_base + i * 16 + lr) * 128
                                                    + ci0 + cs * 32 + lg * 8];
#pragma unroll
            for (int j = 0; j < 4; ++j) {
                const int px = px_base + j * 16 + lr;
                const int r = px >> 6, c = px & 63;
                const int sp = (r + dr) * 66 + c + dc;
#pragma unroll
                for (int cs = 0; cs < 2; ++cs)
                    bfv[cs][j] = *(const short8*)&sIn[sp * 68 + cs * 32 + lg * 8];
            }
#pragma unroll
            for (int cs = 0; cs < 2; ++cs)
#pragma unroll
                for (int i = 0; i < 4; ++i)
#pragma unroll
                    for (int j = 0; j < 4; ++j)
                        acc[i][j] = __builtin_amdgcn_mfma_f32_16x16x32_bf16(af[i][cs], bfv[cs][j],
                                                                            acc[i][j], 0, 0, 0);
        }
    }

    // ---- BN partials: sum/sumsq over this block's 128 px, per co
#pragma unroll
    for (int i = 0; i < 4; ++i)
#pragma unroll
        for (int q = 0; q < 4; ++q) {
            float v = acc[i][0][q] + acc[i][1][q] + acc[i][2][q] + acc[i][3][q];
            float w = acc[i][0][q] * acc[i][0][q] + acc[i][1][q] * acc[i][1][q]
                    + acc[i][2][q] * acc[i][2][q] + acc[i][3][q] * acc[i][3][q];
#pragma unroll
            for (int m = 1; m < 16; m <<= 1) {
                v += __shfl_xor(v, m);
                w += __shfl_xor(w, m);
            }
            if (lr == 0) {
                const int colocal = i * 16 + lg * 4 + q;
                fS[wid * 64 + colocal] = v;
                fQ[wid * 64 + colocal] = w;
            }
        }
    __syncthreads();
    if (tid < 128) {
        const int grp = tid >> 6, cl = tid & 63;
        part[(size_t)b * 256 + tid]       = fS[(grp * 2) * 64 + cl] + fS[(grp * 2 + 1) * 64 + cl];
        part[(size_t)b * 256 + 128 + tid] = fQ[(grp * 2) * 64 + cl] + fQ[(grp * 2 + 1) * 64 + cl];
    }

    // ---- write output
    if (STAGE == 1) {
        // bf16 NHWC: per (i,j): 4 contiguous co -> one 8B store
        const int h = h0 + (px_base >> 6);
#pragma unroll
        for (int j = 0; j < 4; ++j) {
            const int w = j * 16 + lr;
            unsigned short* op = outB + ((size_t)n * 4096 + h * 64 + w) * 128 + co_base + lg * 4;
#pragma unroll
            for (int i = 0; i < 4; ++i) {
                short4v pk;
                pk[0] = (short)f2bf(acc[i][j][0]);
                pk[1] = (short)f2bf(acc[i][j][1]);
                pk[2] = (short)f2bf(acc[i][j][2]);
                pk[3] = (short)f2bf(acc[i][j][3]);
                *(short4v*)&op[i * 16] = pk;
            }
        }
    } else {
        const size_t outN = (size_t)n * 128 * 4096;
#pragma unroll
        for (int i = 0; i < 4; ++i) {
            const int cob = co_base + i * 16 + lg * 4;
#pragma unroll
            for (int q = 0; q < 4; ++q) {
                float* op = outF + outN + (size_t)(cob + q) * 4096 + h0 * 64 + px_base + lr;
#pragma unroll
                for (int j = 0; j < 4; ++j) op[j * 16] = acc[i][j][q];
            }
        }
    }
}

// ---------- fold per-block partials -> per-channel scale/shift ----------
__global__ __launch_bounds__(256) void bn_finalize_k(const float* __restrict__ part,
                                                     const float* __restrict__ gamma,
                                                     const float* __restrict__ beta,
                                                     float* __restrict__ st) {
    const int c = blockIdx.x;
    float s = 0.f, q = 0.f;
    for (int b = threadIdx.x; b < 2048; b += 256) {
        s += part[(size_t)b * 256 + c];
        q += part[(size_t)b * 256 + 128 + c];
    }
    __shared__ float rs[256], rq[256];
    rs[threadIdx.x] = s; rq[threadIdx.x] = q;
    __syncthreads();
    for (int o = 128; o > 0; o >>= 1) {
        if (threadIdx.x < o) {
            rs[threadIdx.x] += rs[threadIdx.x + o];
            rq[threadIdx.x] += rq[threadIdx.x + o];
        }
        __syncthreads();
    }
    if (threadIdx.x == 0) {
        const float inv  = 1.f / (float)NHW;
        const float mean = rs[0] * inv;
        const float var  = rq[0] * inv - mean * mean;
        const float sc   = gamma[c] * rsqrtf(var + EPSF);
        st[c]       = sc;
        st[C_ + c]  = fmaf(-mean, sc, beta[c]);
    }
}

// ---------- per-(n, h-quarter) partial sums of relu(bn(y1)), NHWC bf16 ----------
__global__ __launch_bounds__(256) void maskpart_k(const unsigned short* __restrict__ y1,
                                                  const float* __restrict__ st,
                                                  float* __restrict__ qpart) {
    const int n = blockIdx.x >> 2, hq = blockIdx.x & 3;
    const int c0 = (threadIdx.x & 15) * 8;
    const int sg = threadIdx.x >> 4;  // 0..15
    const float4 s0 = *(const float4*)&st[c0];
    const float4 s1 = *(const float4*)&st[c0 + 4];
    const float4 h0v = *(const float4*)&st[128 + c0];
    const float4 h1v = *(const float4*)&st[128 + c0 + 4];
    float a[8] = {0.f, 0.f, 0.f, 0.f, 0.f, 0.f, 0.f, 0.f};
    const size_t base = (size_t)n * 4096 * 128;
    for (int s = 0; s < 64; ++s) {
        const int sp = hq * 1024 + s * 16 + sg;
        short8 v = *(const short8*)&y1[base + (size_t)sp * 128 + c0];
        a[0] += fmaxf(fmaf(bf2f((unsigned short)v[0]), s0.x, h0v.x), 0.f);
        a[1] += fmaxf(fmaf(bf2f((unsigned short)v[1]), s0.y, h0v.y), 0.f);
        a[2] += fmaxf(fmaf(bf2f((unsigned short)v[2]), s0.z, h0v.z), 0.f);
        a[3] += fmaxf(fmaf(bf2f((unsigned short)v[3]), s0.w, h0v.w), 0.f);
        a[4] += fmaxf(fmaf(bf2f((unsigned short)v[4]), s1.x, h1v.x), 0.f);
        a[5] += fmaxf(fmaf(bf2f((unsigned short)v[5]), s1.y, h1v.y), 0.f);
        a[6] += fmaxf(fmaf(bf2f((unsigned short)v[6]), s1.z, h1v.z), 0.f);
        a[7] += fmaxf(fmaf(bf2f((unsigned short)v[7]), s1.w, h1v.w), 0.f);
    }
    __shared__ float lds[16][128];
#pragma unroll
    for (int k = 0; k < 8; ++k) lds[sg][c0 + k] = a[k];
    __syncthreads();
    if (threadIdx.x < 128) {
        float s = 0.f;
#pragma unroll
        for (int g = 0; g < 16; ++g) s += lds[g][threadIdx.x];
        qpart[(size_t)blockIdx.x * 128 + threadIdx.x] = s;
    }
}

// ---------- finalize mask -> combined ms/mh per (n,c) ----------
__global__ void maskfin_k(const float* __restrict__ qpart, const float* __restrict__ st,
                          float* __restrict__ msA, float* __restrict__ mhA) {
    const int n = blockIdx.x, c = threadIdx.x;
    if (c >= 128) return;
    float s = 0.f;
#pragma unroll
    for (int hq = 0; hq < 4; ++hq) s += qpart[(size_t)(n * 4 + hq) * 128 + c];
    const float m = (s * (1.f / 4096.f) >= THRF) ? 1.f : 0.f;
    msA[n * 128 + c] = st[c] * m;
    mhA[n * 128 + c] = st[128 + c] * m;
}

// ---------- final: relu(bn2(y3) + x), NCHW, in-place on d_out ----------
__global__ __launch_bounds__(256) void final_k(const float* __restrict__ y3,
                                               const float* __restrict__ x,
                                               const float* __restrict__ st,
                                               float* __restrict__ out) {
    const size_t total4 = TENSOR / 4;
    for (size_t i = (size_t)blockIdx.x * 256 + threadIdx.x; i < total4;
         i += (size_t)gridDim.x * 256) {
        const int c = (int)((i >> 10) & (C_ - 1));
        const float sc = st[c], sh = st[C_ + c];
        float4 a = ((const float4*)y3)[i];
        float4 b = ((const float4*)x)[i];
        a.x = fmaxf(fmaf(a.x, sc, sh) + b.x, 0.f);
        a.y = fmaxf(fmaf(a.y, sc, sh) + b.y, 0.f);
        a.z = fmaxf(fmaf(a.z, sc, sh) + b.z, 0.f);
        a.w = fmaxf(fmaf(a.w, sc, sh) + b.w, 0.f);
        ((float4*)out)[i] = a;
    }
}

extern "C" void kernel_launch(void* const* d_in, const int* in_sizes, int n_in,
                              void* d_out, int out_size, void* d_ws, size_t ws_size,
                              hipStream_t stream) {
    const float* x  = (const float*)d_in[0];
    const float* w1 = (const float*)d_in[1];
    const float* g1 = (const float*)d_in[2];
    const float* b1 = (const float*)d_in[3];
    const float* w2 = (const float*)d_in[4];
    const float* g2 = (const float*)d_in[5];
    const float* b2 = (const float*)d_in[6];
    float* out = (float*)d_out;

    // io (x NHWC bf16) lives in d_out's first 67MB (dead until conv2 writes y3 there)
    unsigned short* io = (unsigned short*)d_out;

    char* wsb = (char*)d_ws;
    unsigned short* y1  = (unsigned short*)wsb;                        // 67,108,864 B
    unsigned short* Wt1 = (unsigned short*)(wsb + (size_t)67108864);   // 294,912 B
    unsigned short* Wt2 = Wt1 + 147456;                                // 294,912 B
    float* part  = (float*)(wsb + (size_t)67108864 + 589824);          // 2 MB
    float* st1   = part + 2048 * 256;
    float* st2   = st1 + 256;
    float* qpart = st2 + 256;                                          // 256*128 floats
    float* msA   = qpart + 256 * 128;                                  // 64*128
    float* mhA   = msA + 64 * 128;                                     // 64*128

    prep_w_k<<<1152, 256, 0, stream>>>(w1, w2, Wt1, Wt2);
    // x -> NHWC bf16 (into d_out scratch)
    to_nhwc_k<<<16384, 256, 0, stream>>>(x, io);
    // conv1: io -> y1 (bf16 NHWC) + BN1 partials
    conv_mfma_k<1><<<2048, 256, 0, stream>>>(io, Wt1, nullptr, nullptr, y1, nullptr, part);
    bn_finalize_k<<<128, 256, 0, stream>>>(part, g1, b1, st1);
    // per-(n,c) activation means -> combined mask*scale/shift
    maskpart_k<<<256, 256, 0, stream>>>(y1, st1, qpart);
    maskfin_k<<<64, 128, 0, stream>>>(qpart, st1, msA, mhA);
    // conv2: y1 (BN1+relu+mask applied in staging) -> y3 fp32 NCHW in d_out + BN2 partials
    conv_mfma_k<2><<<2048, 256, 0, stream>>>(y1, Wt2, msA, mhA, nullptr, out, part);
    bn_finalize_k<<<128, 256, 0, stream>>>(part, g2, b2, st2);
    // relu(bn2(y3)+x) in-place on d_out
    final_k<<<8192, 256, 0, stream>>>(out, x, st2, out);
}

// Round 6
// 515.974 us; speedup vs baseline: 1.2894x; 1.0071x over previous
//
#include <hip/hip_runtime.h>

typedef short short8 __attribute__((ext_vector_type(8)));
typedef short short4v __attribute__((ext_vector_type(4)));
typedef float f32x4 __attribute__((ext_vector_type(4)));

#define EPSF 1e-5f
#define THRF 0.2987f

constexpr int N_ = 64, C_ = 128;
constexpr int PLANE = 4096;
constexpr size_t TENSOR = (size_t)N_ * C_ * PLANE;  // 33554432
constexpr int NHW = N_ * PLANE;                     // 262144

__device__ __forceinline__ unsigned short f2bf(float f) {
    unsigned u = __float_as_uint(f);
    u += 0x7fffu + ((u >> 16) & 1u);  // RNE
    return (unsigned short)(u >> 16);
}
__device__ __forceinline__ float bf2f(unsigned short h) {
    return __uint_as_float((unsigned)h << 16);
}

// ---------- weight prep: [co][ci][3][3] fp32 -> [tap][co][ci] bf16 ----------
__global__ __launch_bounds__(256) void prep_w_k(const float* __restrict__ w1,
                                                const float* __restrict__ w2,
                                                unsigned short* __restrict__ Wt1,
                                                unsigned short* __restrict__ Wt2) {
    int idx = blockIdx.x * 256 + threadIdx.x;  // 0..294911
    const int sel = idx >= 147456;
    const float* src = sel ? w2 : w1;
    unsigned short* dst = sel ? Wt2 : Wt1;
    const int r = idx - sel * 147456;
    const int tap = r >> 14;
    const int rem = r & 16383;
    const int co = rem >> 7, ci = rem & 127;
    dst[r] = f2bf(src[(co * 128 + ci) * 9 + tap]);
}

// ---------- NCHW fp32 -> NHWC bf16 transpose (x only) ----------
__global__ __launch_bounds__(256) void to_nhwc_k(const float* __restrict__ src,
                                                 unsigned short* __restrict__ dst) {
    __shared__ __align__(16) unsigned short tl[64 * 40];
    const int b = blockIdx.x;
    const int c0 = (b & 3) * 32;
    const int h  = (b >> 2) & 63;
    const int n  = b >> 8;
    const int t  = threadIdx.x;
    for (int i = t; i < 512; i += 256) {
        const int cl = i >> 4;
        const int c  = c0 + cl;
        const int w4 = (i & 15) * 4;
        float4 v = *(const float4*)&src[(size_t)(n * 128 + c) * 4096 + h * 64 + w4];
        tl[(w4 + 0) * 40 + cl] = f2bf(v.x);
        tl[(w4 + 1) * 40 + cl] = f2bf(v.y);
        tl[(w4 + 2) * 40 + cl] = f2bf(v.z);
        tl[(w4 + 3) * 40 + cl] = f2bf(v.w);
    }
    __syncthreads();
    const int w = t >> 2, cs = t & 3;
    short8 v = *(const short8*)&tl[w * 40 + cs * 8];
    *(short8*)&dst[((size_t)n * 4096 + h * 64 + w) * 128 + c0 + cs * 8] = v;
}

// ---------- conv3x3 MFMA implicit GEMM, fused BN partials ----------
// STAGE 1: in = io (x, bf16 NHWC), out = y1 bf16 NHWC.
// STAGE 2: in = y1; staging applies relu(y*ms+mh) (BN1+relu+mask); out = y3 fp32 NCHW.
// grid 2048 = n(64) x h0(32); 256 thr = 4 waves; tile 128co x (2h x 64w).
// FULL 128-ci input tile staged upfront as two half-layout buffers (zero-conflict
// 68-short stride). ONE barrier pair per block, then 576 MFMA + weight L2 streams
// uninterrupted. LDS 73.9KB -> 2 blocks/CU; staging of one block overlaps compute
// of the other.
template <int STAGE>
__global__ __launch_bounds__(256, 2) void conv_mfma_k(
    const unsigned short* __restrict__ inT, const unsigned short* __restrict__ Wt,
    const float* __restrict__ msA, const float* __restrict__ mhA,
    unsigned short* __restrict__ outB, float* __restrict__ outF,
    float* __restrict__ part) {
    __shared__ __align__(16) short sIn[2 * 264 * 68];  // 71,808 B (two half-tiles)
    __shared__ float fS[256], fQ[256];                 // 2,048 B

    const int b  = blockIdx.x;
    const int h0 = (b & 31) * 2;
    const int n  = b >> 5;
    const int tid  = threadIdx.x;
    const int lane = tid & 63;
    const int wid  = tid >> 6;
    const int co_base = (wid >> 1) * 64;
    const int px_base = (wid & 1) * 64;
    const int lr = lane & 15;
    const int lg = lane >> 4;

    f32x4 acc[4][4];
#pragma unroll
    for (int i = 0; i < 4; ++i)
#pragma unroll
        for (int j = 0; j < 4; ++j) acc[i][j] = (f32x4){0.f, 0.f, 0.f, 0.f};

    const size_t inBase = (size_t)n * 4096 * 128;
    const int nc = n * 128;

    // ---- stage FULL input tile: 264 spatial x 128 ci = 4224 short8 segments
    for (int i = tid; i < 4224; i += 256) {
        const int seg = i & 15;   // ci segment 0..15 (ci = seg*8)
        const int sp  = i >> 4;   // 0..263
        const int r   = sp / 66;
        const int c   = sp - r * 66;
        const int gh  = h0 + r - 1;
        const int gw  = c - 1;
        short8 v = {0, 0, 0, 0, 0, 0, 0, 0};
        if ((unsigned)gh < 64u && (unsigned)gw < 64u) {
            v = *(const short8*)&inT[inBase + ((size_t)gh * 64 + gw) * 128 + seg * 8];
            if (STAGE == 2) {
                const int cb = seg * 8;
                const float4 m0 = *(const float4*)&msA[nc + cb];
                const float4 m1 = *(const float4*)&msA[nc + cb + 4];
                const float4 a0 = *(const float4*)&mhA[nc + cb];
                const float4 a1 = *(const float4*)&mhA[nc + cb + 4];
                short8 w;
                w[0] = (short)f2bf(fmaxf(fmaf(bf2f((unsigned short)v[0]), m0.x, a0.x), 0.f));
                w[1] = (short)f2bf(fmaxf(fmaf(bf2f((unsigned short)v[1]), m0.y, a0.y), 0.f));
                w[2] = (short)f2bf(fmaxf(fmaf(bf2f((unsigned short)v[2]), m0.z, a0.z), 0.f));
                w[3] = (short)f2bf(fmaxf(fmaf(bf2f((unsigned short)v[3]), m0.w, a0.w), 0.f));
                w[4] = (short)f2bf(fmaxf(fmaf(bf2f((unsigned short)v[4]), m1.x, a1.x), 0.f));
                w[5] = (short)f2bf(fmaxf(fmaf(bf2f((unsigned short)v[5]), m1.y, a1.y), 0.f));
                w[6] = (short)f2bf(fmaxf(fmaf(bf2f((unsigned short)v[6]), m1.z, a1.z), 0.f));
                w[7] = (short)f2bf(fmaxf(fmaf(bf2f((unsigned short)v[7]), m1.w, a1.w), 0.f));
                v = w;
            }
        }
        // half = seg>>3 (ci0 0/64), within-half segment = seg&7
        sIn[(seg >> 3) * (264 * 68) + sp * 68 + (seg & 7) * 8] = 0;  // keep layout explicit
        *(short8*)&sIn[(seg >> 3) * (264 * 68) + sp * 68 + (seg & 7) * 8] = v;
    }
    __syncthreads();

    // ---- 576 MFMA uninterrupted; weights stream from L2
#pragma unroll
    for (int half = 0; half < 2; ++half) {
        const int ci0 = half * 64;
        const short* sH = &sIn[half * (264 * 68)];
#pragma unroll
        for (int tap = 0; tap < 9; ++tap) {
            const int dr = tap / 3, dc = tap - dr * 3;
            short8 af[4][2], bfv[2][4];
#pragma unroll
            for (int i = 0; i < 4; ++i)
#pragma unroll
                for (int cs = 0; cs < 2; ++cs)
                    af[i][cs] = *(const short8*)&Wt[((size_t)tap * 128 + co_base + i * 16 + lr) * 128
                                                    + ci0 + cs * 32 + lg * 8];
#pragma unroll
            for (int j = 0; j < 4; ++j) {
                const int px = px_base + j * 16 + lr;
                const int r = px >> 6, c = px & 63;
                const int sp = (r + dr) * 66 + c + dc;
#pragma unroll
                for (int cs = 0; cs < 2; ++cs)
                    bfv[cs][j] = *(const short8*)&sH[sp * 68 + cs * 32 + lg * 8];
            }
#pragma unroll
            for (int cs = 0; cs < 2; ++cs)
#pragma unroll
                for (int i = 0; i < 4; ++i)
#pragma unroll
                    for (int j = 0; j < 4; ++j)
                        acc[i][j] = __builtin_amdgcn_mfma_f32_16x16x32_bf16(af[i][cs], bfv[cs][j],
                                                                            acc[i][j], 0, 0, 0);
        }
    }

    // ---- BN partials: sum/sumsq over this block's 128 px, per co
#pragma unroll
    for (int i = 0; i < 4; ++i)
#pragma unroll
        for (int q = 0; q < 4; ++q) {
            float v = acc[i][0][q] + acc[i][1][q] + acc[i][2][q] + acc[i][3][q];
            float w = acc[i][0][q] * acc[i][0][q] + acc[i][1][q] * acc[i][1][q]
                    + acc[i][2][q] * acc[i][2][q] + acc[i][3][q] * acc[i][3][q];
#pragma unroll
            for (int m = 1; m < 16; m <<= 1) {
                v += __shfl_xor(v, m);
                w += __shfl_xor(w, m);
            }
            if (lr == 0) {
                const int colocal = i * 16 + lg * 4 + q;
                fS[wid * 64 + colocal] = v;
                fQ[wid * 64 + colocal] = w;
            }
        }
    __syncthreads();
    if (tid < 128) {
        const int grp = tid >> 6, cl = tid & 63;
        part[(size_t)b * 256 + tid]       = fS[(grp * 2) * 64 + cl] + fS[(grp * 2 + 1) * 64 + cl];
        part[(size_t)b * 256 + 128 + tid] = fQ[(grp * 2) * 64 + cl] + fQ[(grp * 2 + 1) * 64 + cl];
    }

    // ---- write output
    if (STAGE == 1) {
        const int h = h0 + (px_base >> 6);
#pragma unroll
        for (int j = 0; j < 4; ++j) {
            const int w = j * 16 + lr;
            unsigned short* op = outB + ((size_t)n * 4096 + h * 64 + w) * 128 + co_base + lg * 4;
#pragma unroll
            for (int i = 0; i < 4; ++i) {
                short4v pk;
                pk[0] = (short)f2bf(acc[i][j][0]);
                pk[1] = (short)f2bf(acc[i][j][1]);
                pk[2] = (short)f2bf(acc[i][j][2]);
                pk[3] = (short)f2bf(acc[i][j][3]);
                *(short4v*)&op[i * 16] = pk;
            }
        }
    } else {
        const size_t outN = (size_t)n * 128 * 4096;
#pragma unroll
        for (int i = 0; i < 4; ++i) {
            const int cob = co_base + i * 16 + lg * 4;
#pragma unroll
            for (int q = 0; q < 4; ++q) {
                float* op = outF + outN + (size_t)(cob + q) * 4096 + h0 * 64 + px_base + lr;
#pragma unroll
                for (int j = 0; j < 4; ++j) op[j * 16] = acc[i][j][q];
            }
        }
    }
}

// ---------- fold per-block partials -> per-channel scale/shift ----------
__global__ __launch_bounds__(256) void bn_finalize_k(const float* __restrict__ part,
                                                     const float* __restrict__ gamma,
                                                     const float* __restrict__ beta,
                                                     float* __restrict__ st) {
    const int c = blockIdx.x;
    float s = 0.f, q = 0.f;
    for (int b = threadIdx.x; b < 2048; b += 256) {
        s += part[(size_t)b * 256 + c];
        q += part[(size_t)b * 256 + 128 + c];
    }
    __shared__ float rs[256], rq[256];
    rs[threadIdx.x] = s; rq[threadIdx.x] = q;
    __syncthreads();
    for (int o = 128; o > 0; o >>= 1) {
        if (threadIdx.x < o) {
            rs[threadIdx.x] += rs[threadIdx.x + o];
            rq[threadIdx.x] += rq[threadIdx.x + o];
        }
        __syncthreads();
    }
    if (threadIdx.x == 0) {
        const float inv  = 1.f / (float)NHW;
        const float mean = rs[0] * inv;
        const float var  = rq[0] * inv - mean * mean;
        const float sc   = gamma[c] * rsqrtf(var + EPSF);
        st[c]       = sc;
        st[C_ + c]  = fmaf(-mean, sc, beta[c]);
    }
}

// ---------- per-(n, h-quarter) partial sums of relu(bn(y1)), NHWC bf16 ----------
__global__ __launch_bounds__(256) void maskpart_k(const unsigned short* __restrict__ y1,
                                                  const float* __restrict__ st,
                                                  float* __restrict__ qpart) {
    const int n = blockIdx.x >> 2, hq = blockIdx.x & 3;
    const int c0 = (threadIdx.x & 15) * 8;
    const int sg = threadIdx.x >> 4;  // 0..15
    const float4 s0 = *(const float4*)&st[c0];
    const float4 s1 = *(const float4*)&st[c0 + 4];
    const float4 h0v = *(const float4*)&st[128 + c0];
    const float4 h1v = *(const float4*)&st[128 + c0 + 4];
    float a[8] = {0.f, 0.f, 0.f, 0.f, 0.f, 0.f, 0.f, 0.f};
    const size_t base = (size_t)n * 4096 * 128;
    for (int s = 0; s < 64; ++s) {
        const int sp = hq * 1024 + s * 16 + sg;
        short8 v = *(const short8*)&y1[base + (size_t)sp * 128 + c0];
        a[0] += fmaxf(fmaf(bf2f((unsigned short)v[0]), s0.x, h0v.x), 0.f);
        a[1] += fmaxf(fmaf(bf2f((unsigned short)v[1]), s0.y, h0v.y), 0.f);
        a[2] += fmaxf(fmaf(bf2f((unsigned short)v[2]), s0.z, h0v.z), 0.f);
        a[3] += fmaxf(fmaf(bf2f((unsigned short)v[3]), s0.w, h0v.w), 0.f);
        a[4] += fmaxf(fmaf(bf2f((unsigned short)v[4]), s1.x, h1v.x), 0.f);
        a[5] += fmaxf(fmaf(bf2f((unsigned short)v[5]), s1.y, h1v.y), 0.f);
        a[6] += fmaxf(fmaf(bf2f((unsigned short)v[6]), s1.z, h1v.z), 0.f);
        a[7] += fmaxf(fmaf(bf2f((unsigned short)v[7]), s1.w, h1v.w), 0.f);
    }
    __shared__ float lds[16][128];
#pragma unroll
    for (int k = 0; k < 8; ++k) lds[sg][c0 + k] = a[k];
    __syncthreads();
    if (threadIdx.x < 128) {
        float s = 0.f;
#pragma unroll
        for (int g = 0; g < 16; ++g) s += lds[g][threadIdx.x];
        qpart[(size_t)blockIdx.x * 128 + threadIdx.x] = s;
    }
}

// ---------- finalize mask -> combined ms/mh per (n,c) ----------
__global__ void maskfin_k(const float* __restrict__ qpart, const float* __restrict__ st,
                          float* __restrict__ msA, float* __restrict__ mhA) {
    const int n = blockIdx.x, c = threadIdx.x;
    if (c >= 128) return;
    float s = 0.f;
#pragma unroll
    for (int hq = 0; hq < 4; ++hq) s += qpart[(size_t)(n * 4 + hq) * 128 + c];
    const float m = (s * (1.f / 4096.f) >= THRF) ? 1.f : 0.f;
    msA[n * 128 + c] = st[c] * m;
    mhA[n * 128 + c] = st[128 + c] * m;
}

// ---------- final: relu(bn2(y3) + x), NCHW, in-place on d_out ----------
__global__ __launch_bounds__(256) void final_k(const float* __restrict__ y3,
                                               const float* __restrict__ x,
                                               const float* __restrict__ st,
                                               float* __restrict__ out) {
    const size_t total4 = TENSOR / 4;
    for (size_t i = (size_t)blockIdx.x * 256 + threadIdx.x; i < total4;
         i += (size_t)gridDim.x * 256) {
        const int c = (int)((i >> 10) & (C_ - 1));
        const float sc = st[c], sh = st[C_ + c];
        float4 a = ((const float4*)y3)[i];
        float4 b = ((const float4*)x)[i];
        a.x = fmaxf(fmaf(a.x, sc, sh) + b.x, 0.f);
        a.y = fmaxf(fmaf(a.y, sc, sh) + b.y, 0.f);
        a.z = fmaxf(fmaf(a.z, sc, sh) + b.z, 0.f);
        a.w = fmaxf(fmaf(a.w, sc, sh) + b.w, 0.f);
        ((float4*)out)[i] = a;
    }
}

extern "C" void kernel_launch(void* const* d_in, const int* in_sizes, int n_in,
                              void* d_out, int out_size, void* d_ws, size_t ws_size,
                              hipStream_t stream) {
    const float* x  = (const float*)d_in[0];
    const float* w1 = (const float*)d_in[1];
    const float* g1 = (const float*)d_in[2];
    const float* b1 = (const float*)d_in[3];
    const float* w2 = (const float*)d_in[4];
    const float* g2 = (const float*)d_in[5];
    const float* b2 = (const float*)d_in[6];
    float* out = (float*)d_out;

    // io (x NHWC bf16) lives in d_out's first 67MB (dead until conv2 writes y3 there)
    unsigned short* io = (unsigned short*)d_out;

    char* wsb = (char*)d_ws;
    unsigned short* y1  = (unsigned short*)wsb;                        // 67,108,864 B
    unsigned short* Wt1 = (unsigned short*)(wsb + (size_t)67108864);   // 294,912 B
    unsigned short* Wt2 = Wt1 + 147456;                                // 294,912 B
    float* part  = (float*)(wsb + (size_t)67108864 + 589824);          // 2 MB
    float* st1   = part + 2048 * 256;
    float* st2   = st1 + 256;
    float* qpart = st2 + 256;                                          // 256*128 floats
    float* msA   = qpart + 256 * 128;                                  // 64*128
    float* mhA   = msA + 64 * 128;                                     // 64*128

    prep_w_k<<<1152, 256, 0, stream>>>(w1, w2, Wt1, Wt2);
    to_nhwc_k<<<16384, 256, 0, stream>>>(x, io);
    conv_mfma_k<1><<<2048, 256, 0, stream>>>(io, Wt1, nullptr, nullptr, y1, nullptr, part);
    bn_finalize_k<<<128, 256, 0, stream>>>(part, g1, b1, st1);
    maskpart_k<<<256, 256, 0, stream>>>(y1, st1, qpart);
    maskfin_k<<<64, 128, 0, stream>>>(qpart, st1, msA, mhA);
    conv_mfma_k<2><<<2048, 256, 0, stream>>>(y1, Wt2, msA, mhA, nullptr, out, part);
    bn_finalize_k<<<128, 256, 0, stream>>>(part, g2, b2, st2);
    final_k<<<8192, 256, 0, stream>>>(out, x, st2, out);
}

// Round 8
// 425.583 us; speedup vs baseline: 1.5632x; 1.2124x over previous
//
#include <hip/hip_runtime.h>

typedef short short8 __attribute__((ext_vector_type(8)));
typedef short short4v __attribute__((ext_vector_type(4)));
typedef float f32x4 __attribute__((ext_vector_type(4)));
typedef unsigned int u32;

#define EPSF 1e-5f
#define THRF 0.2987f

constexpr int N_ = 64, C_ = 128;
constexpr int PLANE = 4096;
constexpr size_t TENSOR = (size_t)N_ * C_ * PLANE;  // 33554432
constexpr int NHW = N_ * PLANE;                     // 262144
constexpr int PUNITS = 66 * 66 * 8;                 // 34848 16B-units per (half,n) plane

__device__ __forceinline__ unsigned short f2bf(float f) {
    unsigned u = __float_as_uint(f);
    u += 0x7fffu + ((u >> 16) & 1u);  // RNE
    return (unsigned short)(u >> 16);
}
__device__ __forceinline__ float bf2f(unsigned short h) {
    return __uint_as_float((unsigned)h << 16);
}
__device__ __forceinline__ void gld16(const unsigned short* g, unsigned short* l) {
    __builtin_amdgcn_global_load_lds(
        (const __attribute__((address_space(1))) u32*)g,
        (__attribute__((address_space(3))) u32*)l, 16, 0, 0);
}

// ---------- weight prep: [co][ci][3][3] fp32 -> 36 slices [tap*4+cs][swizzled 128co x 32ci] bf16
// unit(co, cigl) = co*4 + (cigl ^ (co&3)); slice = tap*4 + (ci>>5); cigl = (ci>>3)&3
__global__ __launch_bounds__(256) void prep_w_k(const float* __restrict__ w1,
                                                const float* __restrict__ w2,
                                                unsigned short* __restrict__ Wt1,
                                                unsigned short* __restrict__ Wt2) {
    int idx = blockIdx.x * 256 + threadIdx.x;  // 0..294911
    const int sel = idx >= 147456;
    const float* src = sel ? w2 : w1;
    unsigned short* dst = sel ? Wt2 : Wt1;
    const int r = idx - sel * 147456;
    const int tap = r >> 14;
    const int rem = r & 16383;
    const int co = rem >> 7, ci = rem & 127;
    const int slice = tap * 4 + (ci >> 5);
    const int cigl = (ci >> 3) & 3;
    const int unit = co * 4 + (cigl ^ (co & 3));
    dst[(size_t)slice * 4096 + unit * 8 + (ci & 7)] = f2bf(src[(co * 128 + ci) * 9 + tap]);
}

// ---------- zero the padded borders of io and y1 (2080 units per plane, 128 planes each)
__global__ __launch_bounds__(256) void zero_border_k(unsigned short* __restrict__ io,
                                                     unsigned short* __restrict__ y1) {
    int idx = blockIdx.x * 256 + threadIdx.x;  // 2*128*2080 = 532480
    if (idx >= 532480) return;
    unsigned short* base = (idx >= 266240) ? y1 : io;
    int r = (idx >= 266240) ? idx - 266240 : idx;
    const int plane = r / 2080;
    const int t = r - plane * 2080;
    int sp;
    if (t < 528) sp = t >> 3;                                  // row 0
    else if (t < 1056) sp = 65 * 66 + ((t - 528) >> 3);        // row 65
    else if (t < 1568) sp = (((t - 1056) >> 3) + 1) * 66;      // col 0, rows 1..64
    else sp = (((t - 1568) >> 3) + 1) * 66 + 65;               // col 65
    const size_t off = ((size_t)plane * PUNITS + sp * 8 + (t & 7)) * 8;
    *(short8*)&base[off] = (short8){0, 0, 0, 0, 0, 0, 0, 0};
}

// ---------- NCHW fp32 -> padded swizzled NHWC bf16 (x only) ----------
__global__ __launch_bounds__(256) void to_nhwc_k(const float* __restrict__ src,
                                                 unsigned short* __restrict__ dst) {
    __shared__ __align__(16) unsigned short tl[64 * 40];
    const int b = blockIdx.x;
    const int c0 = (b & 3) * 32;
    const int h  = (b >> 2) & 63;
    const int n  = b >> 8;
    const int t  = threadIdx.x;
    for (int i = t; i < 512; i += 256) {
        const int cl = i >> 4;
        const int c  = c0 + cl;
        const int w4 = (i & 15) * 4;
        float4 v = *(const float4*)&src[(size_t)(n * 128 + c) * 4096 + h * 64 + w4];
        tl[(w4 + 0) * 40 + cl] = f2bf(v.x);
        tl[(w4 + 1) * 40 + cl] = f2bf(v.y);
        tl[(w4 + 2) * 40 + cl] = f2bf(v.z);
        tl[(w4 + 3) * 40 + cl] = f2bf(v.w);
    }
    __syncthreads();
    const int w = t >> 2, cs = t & 3;
    short8 v = *(const short8*)&tl[w * 40 + cs * 8];
    const int c = c0 + cs * 8;
    const int half = c >> 6, cig = (c >> 3) & 7;
    const int colp = w + 1, rowp = h + 1;
    const size_t off = ((size_t)(half * 64 + n) * PUNITS
                        + (size_t)(rowp * 66 + colp) * 8 + (cig ^ (colp & 7))) * 8;
    *(short8*)&dst[off] = v;
}

// ---------- conv3x3 MFMA implicit GEMM, pipelined, fused BN partials ----------
// inT: padded swizzled [2][64][66][66][64ci] bf16. Wt: 36 swizzled 8KB slices.
// STAGE1: input staged via global_load_lds; out = y1 (padded swizzled bf16).
// STAGE2: input reg-staged with BN1+relu+mask transform; out = y3 fp32 NCHW.
// 36 K-steps (tap x 32ci); weights double-buffered via global_load_lds, prefetched
// one step ahead (issue-before-compute). LDS 52.2KB -> 3 blocks/CU.
template <int STAGE>
__global__ __launch_bounds__(256) void conv_mfma_k(
    const unsigned short* __restrict__ inT, const unsigned short* __restrict__ Wt,
    const float* __restrict__ msA, const float* __restrict__ mhA,
    unsigned short* __restrict__ outB, float* __restrict__ outF,
    float* __restrict__ part) {
    __shared__ __align__(16) unsigned short sIn[2112 * 8];   // 33,792 B (4 rows x 66 x 64ci)
    __shared__ __align__(16) unsigned short sW[2][4096];     // 16,384 B
    __shared__ float fS[256], fQ[256];                       // 2,048 B

    const int b  = blockIdx.x;
    const int h0 = (b & 31) * 2;
    const int n  = b >> 5;
    const int tid  = threadIdx.x;
    const int lane = tid & 63;
    const int wid  = tid >> 6;
    const int co_base = (wid >> 1) * 64;
    const int px_base = (wid & 1) * 64;
    const int lr = lane & 15;
    const int lg = lane >> 4;

    f32x4 acc[4][4];
#pragma unroll
    for (int i = 0; i < 4; ++i)
#pragma unroll
        for (int j = 0; j < 4; ++j) acc[i][j] = (f32x4){0.f, 0.f, 0.f, 0.f};

    const int nc = n * 128;

    // --- weight slice prefetch: 512 units; each wave DMAs rows wid*2, wid*2+1
    //     (row r = 64 units -> LDS short-offset r*512, 16B/lane)
    auto stage_w = [&](int slot, int slice) {
        const unsigned short* src = Wt + (size_t)slice * 4096;
        gld16(src + ((wid * 2 + 0) * 64 + lane) * 8, &sW[slot][(wid * 2 + 0) * 512]);
        gld16(src + ((wid * 2 + 1) * 64 + lane) * 8, &sW[slot][(wid * 2 + 1) * 512]);
    };

    // --- input half stage
    auto stage_in = [&](int half) {
        const unsigned short* src =
            inT + ((size_t)(half * 64 + n) * PUNITS + (size_t)h0 * 66 * 8) * 8;
        if (STAGE == 1) {
            for (int c = wid; c < 33; c += 4)
                gld16(src + (c * 64 + lane) * 8, &sIn[c * 512]);
        } else {
            const int ncb = nc + half * 64;
            for (int i = tid; i < 2112; i += 256) {
                short8 v = *(const short8*)&src[i * 8];
                const int sp = i >> 3, ul = i & 7;
                const int rq = sp / 66;
                const int colp = sp - rq * 66;
                const int rp = h0 + rq;
                if (rp != 0 && rp != 65 && colp != 0 && colp != 65) {
                    const int cig = ul ^ (colp & 7);
                    const int cb = ncb + cig * 8;
                    const float4 m0 = *(const float4*)&msA[cb];
                    const float4 m1 = *(const float4*)&msA[cb + 4];
                    const float4 a0 = *(const float4*)&mhA[cb];
                    const float4 a1 = *(const float4*)&mhA[cb + 4];
                    short8 w;
                    w[0] = (short)f2bf(fmaxf(fmaf(bf2f((unsigned short)v[0]), m0.x, a0.x), 0.f));
                    w[1] = (short)f2bf(fmaxf(fmaf(bf2f((unsigned short)v[1]), m0.y, a0.y), 0.f));
                    w[2] = (short)f2bf(fmaxf(fmaf(bf2f((unsigned short)v[2]), m0.z, a0.z), 0.f));
                    w[3] = (short)f2bf(fmaxf(fmaf(bf2f((unsigned short)v[3]), m0.w, a0.w), 0.f));
                    w[4] = (short)f2bf(fmaxf(fmaf(bf2f((unsigned short)v[4]), m1.x, a1.x), 0.f));
                    w[5] = (short)f2bf(fmaxf(fmaf(bf2f((unsigned short)v[5]), m1.y, a1.y), 0.f));
                    w[6] = (short)f2bf(fmaxf(fmaf(bf2f((unsigned short)v[6]), m1.z, a1.z), 0.f));
                    w[7] = (short)f2bf(fmaxf(fmaf(bf2f((unsigned short)v[7]), m1.w, a1.w), 0.f));
                    v = w;
                }
                *(short8*)&sIn[i * 8] = v;
            }
        }
    };

    // prologue: input half0 + first weight slice
    stage_in(0);
    stage_w(0, 0);
    __syncthreads();

#pragma unroll
    for (int half = 0; half < 2; ++half) {
        if (half == 1) {
            stage_in(1);
            __syncthreads();
        }
#pragma unroll
        for (int tap = 0; tap < 9; ++tap) {
#pragma unroll
            for (int csh = 0; csh < 2; ++csh) {
                const int s = half * 18 + tap * 2 + csh;
                if (s < 35) {
                    const int sn = s + 1;
                    const int nh = sn / 18, nt = (sn % 18) / 2, nc2 = sn & 1;
                    stage_w(sn & 1, nt * 4 + nh * 2 + nc2);
                }
                const int dr = tap / 3, dc = tap - dr * 3;
                const unsigned short* wb = sW[s & 1];
                short8 af[4], bfv[4];
#pragma unroll
                for (int i = 0; i < 4; ++i) {
                    const int co = co_base + i * 16 + lr;
                    af[i] = *(const short8*)&wb[(co * 4 + (lg ^ (co & 3))) * 8];
                }
#pragma unroll
                for (int j = 0; j < 4; ++j) {
                    const int px = px_base + j * 16 + lr;
                    const int r = px >> 6, c = px & 63;
                    const int colp = c + dc;
                    const int sp = (r + dr) * 66 + colp;
                    const int cig = csh * 4 + lg;
                    bfv[j] = *(const short8*)&sIn[(sp * 8 + (cig ^ (colp & 7))) * 8];
                }
#pragma unroll
                for (int i = 0; i < 4; ++i)
#pragma unroll
                    for (int j = 0; j < 4; ++j)
                        acc[i][j] = __builtin_amdgcn_mfma_f32_16x16x32_bf16(af[i], bfv[j],
                                                                            acc[i][j], 0, 0, 0);
                __syncthreads();
            }
        }
    }

    // ---- BN partials: sum/sumsq over this block's 128 px, per co
#pragma unroll
    for (int i = 0; i < 4; ++i)
#pragma unroll
        for (int q = 0; q < 4; ++q) {
            float v = acc[i][0][q] + acc[i][1][q] + acc[i][2][q] + acc[i][3][q];
            float w = acc[i][0][q] * acc[i][0][q] + acc[i][1][q] * acc[i][1][q]
                    + acc[i][2][q] * acc[i][2][q] + acc[i][3][q] * acc[i][3][q];
#pragma unroll
            for (int m = 1; m < 16; m <<= 1) {
                v += __shfl_xor(v, m);
                w += __shfl_xor(w, m);
            }
            if (lr == 0) {
                const int colocal = i * 16 + lg * 4 + q;
                fS[wid * 64 + colocal] = v;
                fQ[wid * 64 + colocal] = w;
            }
        }
    __syncthreads();
    if (tid < 128) {
        const int grp = tid >> 6, cl = tid & 63;
        part[(size_t)b * 256 + tid]       = fS[(grp * 2) * 64 + cl] + fS[(grp * 2 + 1) * 64 + cl];
        part[(size_t)b * 256 + 128 + tid] = fQ[(grp * 2) * 64 + cl] + fQ[(grp * 2 + 1) * 64 + cl];
    }

    // ---- write output
    if (STAGE == 1) {
        // y1 padded swizzled bf16
        const int h = h0 + (px_base >> 6);
        const int rowp = h + 1;
        const size_t plane = (size_t)((co_base >> 6) * 64 + n) * PUNITS * 8;
#pragma unroll
        for (int j = 0; j < 4; ++j) {
            const int w = j * 16 + lr;
            const int colp = w + 1;
#pragma unroll
            for (int i = 0; i < 4; ++i) {
                const int cb = co_base + i * 16 + lg * 4;
                const int cig = (cb >> 3) & 7;
                const size_t off = plane
                    + ((size_t)(rowp * 66 + colp) * 8 + (cig ^ (colp & 7))) * 8 + (cb & 7);
                short4v pk;
                pk[0] = (short)f2bf(acc[i][j][0]);
                pk[1] = (short)f2bf(acc[i][j][1]);
                pk[2] = (short)f2bf(acc[i][j][2]);
                pk[3] = (short)f2bf(acc[i][j][3]);
                *(short4v*)&outB[off] = pk;
            }
        }
    } else {
        const size_t outN = (size_t)n * 128 * 4096;
#pragma unroll
        for (int i = 0; i < 4; ++i) {
            const int cob = co_base + i * 16 + lg * 4;
#pragma unroll
            for (int q = 0; q < 4; ++q) {
                float* op = outF + outN + (size_t)(cob + q) * 4096 + h0 * 64 + px_base + lr;
#pragma unroll
                for (int j = 0; j < 4; ++j) op[j * 16] = acc[i][j][q];
            }
        }
    }
}

// ---------- fold per-block partials -> per-channel scale/shift ----------
__global__ __launch_bounds__(256) void bn_finalize_k(const float* __restrict__ part,
                                                     const float* __restrict__ gamma,
                                                     const float* __restrict__ beta,
                                                     float* __restrict__ st) {
    const int c = blockIdx.x;
    float s = 0.f, q = 0.f;
    for (int b = threadIdx.x; b < 2048; b += 256) {
        s += part[(size_t)b * 256 + c];
        q += part[(size_t)b * 256 + 128 + c];
    }
    __shared__ float rs[256], rq[256];
    rs[threadIdx.x] = s; rq[threadIdx.x] = q;
    __syncthreads();
    for (int o = 128; o > 0; o >>= 1) {
        if (threadIdx.x < o) {
            rs[threadIdx.x] += rs[threadIdx.x + o];
            rq[threadIdx.x] += rq[threadIdx.x + o];
        }
        __syncthreads();
    }
    if (threadIdx.x == 0) {
        const float inv  = 1.f / (float)NHW;
        const float mean = rs[0] * inv;
        const float var  = rq[0] * inv - mean * mean;
        const float sc   = gamma[c] * rsqrtf(var + EPSF);
        st[c]       = sc;
        st[C_ + c]  = fmaf(-mean, sc, beta[c]);
    }
}

// ---------- per-(n,half) sums of relu(bn1(y1)) over the interior, swizzled layout ----------
__global__ __launch_bounds__(256) void maskpart_k(const unsigned short* __restrict__ y1,
                                                  const float* __restrict__ st,
                                                  float* __restrict__ qsum) {
    const int n = blockIdx.x >> 1, half = blockIdx.x & 1;
    const int t = threadIdx.x;
    const int colg = t & 63;
    const int p = t >> 6;  // cig pair {2p, 2p+1}
    const int colp = 1 + colg;
    float scv[2][8], shv[2][8], a[2][8];
#pragma unroll
    for (int k = 0; k < 2; ++k)
#pragma unroll
        for (int e = 0; e < 8; ++e) {
            const int c = half * 64 + (2 * p + k) * 8 + e;
            scv[k][e] = st[c];
            shv[k][e] = st[128 + c];
            a[k][e] = 0.f;
        }
    const size_t plane = (size_t)(half * 64 + n) * PUNITS * 8;
    for (int rowp = 1; rowp <= 64; ++rowp) {
        const int sp = rowp * 66 + colp;
#pragma unroll
        for (int k = 0; k < 2; ++k) {
            const int cig = 2 * p + k;
            short8 v = *(const short8*)&y1[plane + ((size_t)sp * 8 + (cig ^ (colp & 7))) * 8];
#pragma unroll
            for (int e = 0; e < 8; ++e)
                a[k][e] += fmaxf(fmaf(bf2f((unsigned short)v[e]), scv[k][e], shv[k][e]), 0.f);
        }
    }
    __shared__ float lds[256][16];
#pragma unroll
    for (int k = 0; k < 2; ++k)
#pragma unroll
        for (int e = 0; e < 8; ++e) lds[t][k * 8 + e] = a[k][e];
    __syncthreads();
    if (t < 64) {
        const int cig = t >> 3, e = t & 7, p2 = cig >> 1, k2 = cig & 1;
        float s = 0.f;
        for (int cg = 0; cg < 64; ++cg) s += lds[p2 * 64 + cg][k2 * 8 + e];
        qsum[(size_t)(n * 2 + half) * 64 + t] = s;
    }
}

// ---------- finalize mask -> combined ms/mh per (n,c) ----------
__global__ void maskfin_k(const float* __restrict__ qsum, const float* __restrict__ st,
                          float* __restrict__ msA, float* __restrict__ mhA) {
    const int n = blockIdx.x, c = threadIdx.x;
    if (c >= 128) return;
    const int half = c >> 6, cl = c & 63;
    const float s = qsum[(size_t)(n * 2 + half) * 64 + cl];
    const float m = (s * (1.f / 4096.f) >= THRF) ? 1.f : 0.f;
    msA[n * 128 + c] = st[c] * m;
    mhA[n * 128 + c] = st[128 + c] * m;
}

// ---------- final: relu(bn2(y3) + x), NCHW ----------
__global__ __launch_bounds__(256) void final_k(const float* __restrict__ y3,
                                               const float* __restrict__ x,
                                               const float* __restrict__ st,
                                               float* __restrict__ out) {
    const size_t total4 = TENSOR / 4;
    for (size_t i = (size_t)blockIdx.x * 256 + threadIdx.x; i < total4;
         i += (size_t)gridDim.x * 256) {
        const int c = (int)((i >> 10) & (C_ - 1));
        const float sc = st[c], sh = st[C_ + c];
        float4 a = ((const float4*)y3)[i];
        float4 b = ((const float4*)x)[i];
        a.x = fmaxf(fmaf(a.x, sc, sh) + b.x, 0.f);
        a.y = fmaxf(fmaf(a.y, sc, sh) + b.y, 0.f);
        a.z = fmaxf(fmaf(a.z, sc, sh) + b.z, 0.f);
        a.w = fmaxf(fmaf(a.w, sc, sh) + b.w, 0.f);
        ((float4*)out)[i] = a;
    }
}

extern "C" void kernel_launch(void* const* d_in, const int* in_sizes, int n_in,
                              void* d_out, int out_size, void* d_ws, size_t ws_size,
                              hipStream_t stream) {
    const float* x  = (const float*)d_in[0];
    const float* w1 = (const float*)d_in[1];
    const float* g1 = (const float*)d_in[2];
    const float* b1 = (const float*)d_in[3];
    const float* w2 = (const float*)d_in[4];
    const float* g2 = (const float*)d_in[5];
    const float* b2 = (const float*)d_in[6];
    float* out = (float*)d_out;

    // io (padded swizzled x, 71.4MB) lives in d_out (dead until conv2 writes y3)
    unsigned short* io = (unsigned short*)d_out;

    char* wsb = (char*)d_ws;
    unsigned short* y1  = (unsigned short*)wsb;                        // 71,368,704 B
    unsigned short* Wt1 = (unsigned short*)(wsb + (size_t)71368704);   // 294,912 B
    unsigned short* Wt2 = Wt1 + 147456;                                // 294,912 B
    float* part  = (float*)(wsb + (size_t)71368704 + 589824);          // 2 MB
    float* st1   = part + 2048 * 256;
    float* st2   = st1 + 256;
    float* qsum  = st2 + 256;                                          // 128*64 floats
    float* msA   = qsum + 128 * 64;                                    // 64*128
    float* mhA   = msA + 64 * 128;                                     // 64*128

    prep_w_k<<<1152, 256, 0, stream>>>(w1, w2, Wt1, Wt2);
    zero_border_k<<<2080, 256, 0, stream>>>(io, y1);
    to_nhwc_k<<<16384, 256, 0, stream>>>(x, io);
    // conv1: io -> y1 (padded swizzled bf16) + BN1 partials
    conv_mfma_k<1><<<2048, 256, 0, stream>>>(io, Wt1, nullptr, nullptr, y1, nullptr, part);
    bn_finalize_k<<<128, 256, 0, stream>>>(part, g1, b1, st1);
    maskpart_k<<<128, 256, 0, stream>>>(y1, st1, qsum);
    maskfin_k<<<64, 128, 0, stream>>>(qsum, st1, msA, mhA);
    // conv2: y1 (BN1+relu+mask in staging) -> y3 fp32 NCHW in d_out + BN2 partials
    conv_mfma_k<2><<<2048, 256, 0, stream>>>(y1, Wt2, msA, mhA, nullptr, out, part);
    bn_finalize_k<<<128, 256, 0, stream>>>(part, g2, b2, st2);
    final_k<<<8192, 256, 0, stream>>>(out, x, st2, out);
}

// Round 9
// 418.946 us; speedup vs baseline: 1.5880x; 1.0158x over previous
//
#include <hip/hip_runtime.h>

typedef short short8 __attribute__((ext_vector_type(8)));
typedef short short4v __attribute__((ext_vector_type(4)));
typedef float f32x4 __attribute__((ext_vector_type(4)));
typedef unsigned int u32;

#define EPSF 1e-5f
#define THRF 0.2987f

#define VMCNT0 asm volatile("s_waitcnt vmcnt(0)" ::: "memory")
#define VMCNT2 asm volatile("s_waitcnt vmcnt(2)" ::: "memory")
#define LGKM0  asm volatile("s_waitcnt lgkmcnt(0)" ::: "memory")

constexpr int N_ = 64, C_ = 128;
constexpr int PLANE = 4096;
constexpr size_t TENSOR = (size_t)N_ * C_ * PLANE;  // 33554432
constexpr int NHW = N_ * PLANE;                     // 262144
constexpr int PUNITS = 66 * 66 * 8;                 // 34848 16B-units per (half,n) plane

__device__ __forceinline__ unsigned short f2bf(float f) {
    unsigned u = __float_as_uint(f);
    u += 0x7fffu + ((u >> 16) & 1u);  // RNE
    return (unsigned short)(u >> 16);
}
__device__ __forceinline__ float bf2f(unsigned short h) {
    return __uint_as_float((unsigned)h << 16);
}
__device__ __forceinline__ void gld16(const unsigned short* g, unsigned short* l) {
    __builtin_amdgcn_global_load_lds(
        (const __attribute__((address_space(1))) u32*)g,
        (__attribute__((address_space(3))) u32*)l, 16, 0, 0);
}
// step s -> weight slice id in Wt (slice = tap*4 + half*2 + csh)
__host__ __device__ constexpr int sliceOf(int s) {
    return ((s % 18) >> 1) * 4 + (s / 18) * 2 + (s & 1);
}

// ---------- weight prep: [co][ci][3][3] fp32 -> 36 slices [tap*4+cs][swizzled 128co x 32ci] bf16
__global__ __launch_bounds__(256) void prep_w_k(const float* __restrict__ w1,
                                                const float* __restrict__ w2,
                                                unsigned short* __restrict__ Wt1,
                                                unsigned short* __restrict__ Wt2) {
    int idx = blockIdx.x * 256 + threadIdx.x;  // 0..294911
    const int sel = idx >= 147456;
    const float* src = sel ? w2 : w1;
    unsigned short* dst = sel ? Wt2 : Wt1;
    const int r = idx - sel * 147456;
    const int tap = r >> 14;
    const int rem = r & 16383;
    const int co = rem >> 7, ci = rem & 127;
    const int slice = tap * 4 + (ci >> 5);
    const int cigl = (ci >> 3) & 3;
    const int unit = co * 4 + (cigl ^ (co & 3));
    dst[(size_t)slice * 4096 + unit * 8 + (ci & 7)] = f2bf(src[(co * 128 + ci) * 9 + tap]);
}

// ---------- zero the padded borders of io and y1 ----------
__global__ __launch_bounds__(256) void zero_border_k(unsigned short* __restrict__ io,
                                                     unsigned short* __restrict__ y1) {
    int idx = blockIdx.x * 256 + threadIdx.x;  // 2*128*2080 = 532480
    if (idx >= 532480) return;
    unsigned short* base = (idx >= 266240) ? y1 : io;
    int r = (idx >= 266240) ? idx - 266240 : idx;
    const int plane = r / 2080;
    const int t = r - plane * 2080;
    int sp;
    if (t < 528) sp = t >> 3;
    else if (t < 1056) sp = 65 * 66 + ((t - 528) >> 3);
    else if (t < 1568) sp = (((t - 1056) >> 3) + 1) * 66;
    else sp = (((t - 1568) >> 3) + 1) * 66 + 65;
    const size_t off = ((size_t)plane * PUNITS + sp * 8 + (t & 7)) * 8;
    *(short8*)&base[off] = (short8){0, 0, 0, 0, 0, 0, 0, 0};
}

// ---------- NCHW fp32 -> padded swizzled NHWC bf16 (x only) ----------
__global__ __launch_bounds__(256) void to_nhwc_k(const float* __restrict__ src,
                                                 unsigned short* __restrict__ dst) {
    __shared__ __align__(16) unsigned short tl[64 * 40];
    const int b = blockIdx.x;
    const int c0 = (b & 3) * 32;
    const int h  = (b >> 2) & 63;
    const int n  = b >> 8;
    const int t  = threadIdx.x;
    for (int i = t; i < 512; i += 256) {
        const int cl = i >> 4;
        const int c  = c0 + cl;
        const int w4 = (i & 15) * 4;
        float4 v = *(const float4*)&src[(size_t)(n * 128 + c) * 4096 + h * 64 + w4];
        tl[(w4 + 0) * 40 + cl] = f2bf(v.x);
        tl[(w4 + 1) * 40 + cl] = f2bf(v.y);
        tl[(w4 + 2) * 40 + cl] = f2bf(v.z);
        tl[(w4 + 3) * 40 + cl] = f2bf(v.w);
    }
    __syncthreads();
    const int w = t >> 2, cs = t & 3;
    short8 v = *(const short8*)&tl[w * 40 + cs * 8];
    const int c = c0 + cs * 8;
    const int half = c >> 6, cig = (c >> 3) & 7;
    const int colp = w + 1, rowp = h + 1;
    const size_t off = ((size_t)(half * 64 + n) * PUNITS
                        + (size_t)(rowp * 66 + colp) * 8 + (cig ^ (colp & 7))) * 8;
    *(short8*)&dst[off] = v;
}

// ---------- conv3x3 MFMA implicit GEMM, counted-vmcnt pipelined ----------
// 36 K-steps (tap x 32ci). Weights: 3-slot LDS ring via global_load_lds, staged
// 2 steps ahead AFTER the step barrier; per-step wait = vmcnt(2) (slice s+1 stays
// in flight) + naked s_barrier. No vmcnt(0)/lgkmcnt(0) drain in the main loop.
template <int STAGE>
__global__ __launch_bounds__(256) void conv_mfma_k(
    const unsigned short* __restrict__ inT, const unsigned short* __restrict__ Wt,
    const float* __restrict__ msA, const float* __restrict__ mhA,
    unsigned short* __restrict__ outB, float* __restrict__ outF,
    float* __restrict__ part) {
    __shared__ __align__(16) unsigned short sIn[2112 * 8];  // 33,792 B
    __shared__ __align__(16) unsigned short sW[3][4096];    // 24,576 B (3-slot ring)
    __shared__ float fS[256], fQ[256];                      // 2,048 B

    const int b  = blockIdx.x;
    const int h0 = (b & 31) * 2;
    const int n  = b >> 5;
    const int tid  = threadIdx.x;
    const int lane = tid & 63;
    const int wid  = tid >> 6;
    const int co_base = (wid >> 1) * 64;
    const int px_base = (wid & 1) * 64;
    const int lr = lane & 15;
    const int lg = lane >> 4;

    f32x4 acc[4][4];
#pragma unroll
    for (int i = 0; i < 4; ++i)
#pragma unroll
        for (int j = 0; j < 4; ++j) acc[i][j] = (f32x4){0.f, 0.f, 0.f, 0.f};

    const int nc = n * 128;

    auto stage_w = [&](int slot, int slice) {
        const unsigned short* src = Wt + (size_t)slice * 4096;
        gld16(src + ((wid * 2 + 0) * 64 + lane) * 8, &sW[slot][(wid * 2 + 0) * 512]);
        gld16(src + ((wid * 2 + 1) * 64 + lane) * 8, &sW[slot][(wid * 2 + 1) * 512]);
    };

    auto stage_in = [&](int half) {
        const unsigned short* src =
            inT + ((size_t)(half * 64 + n) * PUNITS + (size_t)h0 * 66 * 8) * 8;
        if (STAGE == 1) {
            for (int c = wid; c < 33; c += 4)
                gld16(src + (c * 64 + lane) * 8, &sIn[c * 512]);
        } else {
            const int ncb = nc + half * 64;
            for (int i = tid; i < 2112; i += 256) {
                short8 v = *(const short8*)&src[i * 8];
                const int sp = i >> 3, ul = i & 7;
                const int rq = sp / 66;
                const int colp = sp - rq * 66;
                const int rp = h0 + rq;
                if (rp != 0 && rp != 65 && colp != 0 && colp != 65) {
                    const int cig = ul ^ (colp & 7);
                    const int cb = ncb + cig * 8;
                    const float4 m0 = *(const float4*)&msA[cb];
                    const float4 m1 = *(const float4*)&msA[cb + 4];
                    const float4 a0 = *(const float4*)&mhA[cb];
                    const float4 a1 = *(const float4*)&mhA[cb + 4];
                    short8 w;
                    w[0] = (short)f2bf(fmaxf(fmaf(bf2f((unsigned short)v[0]), m0.x, a0.x), 0.f));
                    w[1] = (short)f2bf(fmaxf(fmaf(bf2f((unsigned short)v[1]), m0.y, a0.y), 0.f));
                    w[2] = (short)f2bf(fmaxf(fmaf(bf2f((unsigned short)v[2]), m0.z, a0.z), 0.f));
                    w[3] = (short)f2bf(fmaxf(fmaf(bf2f((unsigned short)v[3]), m0.w, a0.w), 0.f));
                    w[4] = (short)f2bf(fmaxf(fmaf(bf2f((unsigned short)v[4]), m1.x, a1.x), 0.f));
                    w[5] = (short)f2bf(fmaxf(fmaf(bf2f((unsigned short)v[5]), m1.y, a1.y), 0.f));
                    w[6] = (short)f2bf(fmaxf(fmaf(bf2f((unsigned short)v[6]), m1.z, a1.z), 0.f));
                    w[7] = (short)f2bf(fmaxf(fmaf(bf2f((unsigned short)v[7]), m1.w, a1.w), 0.f));
                    v = w;
                }
                *(short8*)&sIn[i * 8] = v;
            }
        }
    };

    // ---- prologue: input half0 + weight slices for steps 0,1; single full sync
    stage_in(0);
    stage_w(0, sliceOf(0));
    stage_w(1, sliceOf(1));
    if (STAGE == 2) { LGKM0; }
    VMCNT2;  // inputs + slice(0) done; slice(1) stays in flight
    __builtin_amdgcn_s_barrier();
    __builtin_amdgcn_sched_barrier(0);

#pragma unroll
    for (int s = 0; s < 36; ++s) {
        if (s > 0) {
            if (s == 35) { VMCNT0; } else { VMCNT2; }  // slice(s) ready; slice(s+1) in flight
            __builtin_amdgcn_s_barrier();
            __builtin_amdgcn_sched_barrier(0);
        }
        if (s == 18) {
            // input half transition: sIn reads (s=17) retired by the barrier above
            stage_in(1);
            stage_w((s + 2) % 3, sliceOf(s + 2));
            if (STAGE == 1) { VMCNT2; } else { LGKM0; }  // half1 staged; slice(20) in flight
            __builtin_amdgcn_s_barrier();
            __builtin_amdgcn_sched_barrier(0);
        } else if (s + 2 < 36) {
            stage_w((s + 2) % 3, sliceOf(s + 2));  // after barrier: old readers retired
        }
        // ---- compute step s
        const int tap = (s % 18) >> 1, csh = s & 1;
        const int dr = tap / 3, dc = tap - dr * 3;
        const unsigned short* wb = &sW[s % 3][0];
        short8 af[4], bfv[4];
#pragma unroll
        for (int i = 0; i < 4; ++i) {
            const int co = co_base + i * 16 + lr;
            af[i] = *(const short8*)&wb[(co * 4 + (lg ^ (co & 3))) * 8];
        }
#pragma unroll
        for (int j = 0; j < 4; ++j) {
            const int px = px_base + j * 16 + lr;
            const int r = px >> 6, c = px & 63;
            const int colp = c + dc;
            const int sp = (r + dr) * 66 + colp;
            const int cig = csh * 4 + lg;
            bfv[j] = *(const short8*)&sIn[(sp * 8 + (cig ^ (colp & 7))) * 8];
        }
#pragma unroll
        for (int i = 0; i < 4; ++i)
#pragma unroll
            for (int j = 0; j < 4; ++j)
                acc[i][j] = __builtin_amdgcn_mfma_f32_16x16x32_bf16(af[i], bfv[j],
                                                                    acc[i][j], 0, 0, 0);
    }

    // ---- BN partials: sum/sumsq over this block's 128 px, per co
#pragma unroll
    for (int i = 0; i < 4; ++i)
#pragma unroll
        for (int q = 0; q < 4; ++q) {
            float v = acc[i][0][q] + acc[i][1][q] + acc[i][2][q] + acc[i][3][q];
            float w = acc[i][0][q] * acc[i][0][q] + acc[i][1][q] * acc[i][1][q]
                    + acc[i][2][q] * acc[i][2][q] + acc[i][3][q] * acc[i][3][q];
#pragma unroll
            for (int m = 1; m < 16; m <<= 1) {
                v += __shfl_xor(v, m);
                w += __shfl_xor(w, m);
            }
            if (lr == 0) {
                const int colocal = i * 16 + lg * 4 + q;
                fS[wid * 64 + colocal] = v;
                fQ[wid * 64 + colocal] = w;
            }
        }
    __syncthreads();
    if (tid < 128) {
        const int grp = tid >> 6, cl = tid & 63;
        part[(size_t)b * 256 + tid]       = fS[(grp * 2) * 64 + cl] + fS[(grp * 2 + 1) * 64 + cl];
        part[(size_t)b * 256 + 128 + tid] = fQ[(grp * 2) * 64 + cl] + fQ[(grp * 2 + 1) * 64 + cl];
    }

    // ---- write output
    if (STAGE == 1) {
        const int h = h0 + (px_base >> 6);
        const int rowp = h + 1;
        const size_t plane = (size_t)((co_base >> 6) * 64 + n) * PUNITS * 8;
#pragma unroll
        for (int j = 0; j < 4; ++j) {
            const int w = j * 16 + lr;
            const int colp = w + 1;
#pragma unroll
            for (int i = 0; i < 4; ++i) {
                const int cb = co_base + i * 16 + lg * 4;
                const int cig = (cb >> 3) & 7;
                const size_t off = plane
                    + ((size_t)(rowp * 66 + colp) * 8 + (cig ^ (colp & 7))) * 8 + (cb & 7);
                short4v pk;
                pk[0] = (short)f2bf(acc[i][j][0]);
                pk[1] = (short)f2bf(acc[i][j][1]);
                pk[2] = (short)f2bf(acc[i][j][2]);
                pk[3] = (short)f2bf(acc[i][j][3]);
                *(short4v*)&outB[off] = pk;
            }
        }
    } else {
        const size_t outN = (size_t)n * 128 * 4096;
#pragma unroll
        for (int i = 0; i < 4; ++i) {
            const int cob = co_base + i * 16 + lg * 4;
#pragma unroll
            for (int q = 0; q < 4; ++q) {
                float* op = outF + outN + (size_t)(cob + q) * 4096 + h0 * 64 + px_base + lr;
#pragma unroll
                for (int j = 0; j < 4; ++j) op[j * 16] = acc[i][j][q];
            }
        }
    }
}

// ---------- fold per-block partials -> per-channel scale/shift ----------
__global__ __launch_bounds__(256) void bn_finalize_k(const float* __restrict__ part,
                                                     const float* __restrict__ gamma,
                                                     const float* __restrict__ beta,
                                                     float* __restrict__ st) {
    const int c = blockIdx.x;
    float s = 0.f, q = 0.f;
    for (int b = threadIdx.x; b < 2048; b += 256) {
        s += part[(size_t)b * 256 + c];
        q += part[(size_t)b * 256 + 128 + c];
    }
    __shared__ float rs[256], rq[256];
    rs[threadIdx.x] = s; rq[threadIdx.x] = q;
    __syncthreads();
    for (int o = 128; o > 0; o >>= 1) {
        if (threadIdx.x < o) {
            rs[threadIdx.x] += rs[threadIdx.x + o];
            rq[threadIdx.x] += rq[threadIdx.x + o];
        }
        __syncthreads();
    }
    if (threadIdx.x == 0) {
        const float inv  = 1.f / (float)NHW;
        const float mean = rs[0] * inv;
        const float var  = rq[0] * inv - mean * mean;
        const float sc   = gamma[c] * rsqrtf(var + EPSF);
        st[c]       = sc;
        st[C_ + c]  = fmaf(-mean, sc, beta[c]);
    }
}

// ---------- per-(n,half) sums of relu(bn1(y1)) over the interior ----------
__global__ __launch_bounds__(256) void maskpart_k(const unsigned short* __restrict__ y1,
                                                  const float* __restrict__ st,
                                                  float* __restrict__ qsum) {
    const int n = blockIdx.x >> 1, half = blockIdx.x & 1;
    const int t = threadIdx.x;
    const int colg = t & 63;
    const int p = t >> 6;
    const int colp = 1 + colg;
    float scv[2][8], shv[2][8], a[2][8];
#pragma unroll
    for (int k = 0; k < 2; ++k)
#pragma unroll
        for (int e = 0; e < 8; ++e) {
            const int c = half * 64 + (2 * p + k) * 8 + e;
            scv[k][e] = st[c];
            shv[k][e] = st[128 + c];
            a[k][e] = 0.f;
        }
    const size_t plane = (size_t)(half * 64 + n) * PUNITS * 8;
    for (int rowp = 1; rowp <= 64; ++rowp) {
        const int sp = rowp * 66 + colp;
#pragma unroll
        for (int k = 0; k < 2; ++k) {
            const int cig = 2 * p + k;
            short8 v = *(const short8*)&y1[plane + ((size_t)sp * 8 + (cig ^ (colp & 7))) * 8];
#pragma unroll
            for (int e = 0; e < 8; ++e)
                a[k][e] += fmaxf(fmaf(bf2f((unsigned short)v[e]), scv[k][e], shv[k][e]), 0.f);
        }
    }
    __shared__ float lds[256][16];
#pragma unroll
    for (int k = 0; k < 2; ++k)
#pragma unroll
        for (int e = 0; e < 8; ++e) lds[t][k * 8 + e] = a[k][e];
    __syncthreads();
    if (t < 64) {
        const int cig = t >> 3, e = t & 7, p2 = cig >> 1, k2 = cig & 1;
        float s = 0.f;
        for (int cg = 0; cg < 64; ++cg) s += lds[p2 * 64 + cg][k2 * 8 + e];
        qsum[(size_t)(n * 2 + half) * 64 + t] = s;
    }
}

// ---------- finalize mask -> combined ms/mh per (n,c) ----------
__global__ void maskfin_k(const float* __restrict__ qsum, const float* __restrict__ st,
                          float* __restrict__ msA, float* __restrict__ mhA) {
    const int n = blockIdx.x, c = threadIdx.x;
    if (c >= 128) return;
    const int half = c >> 6, cl = c & 63;
    const float s = qsum[(size_t)(n * 2 + half) * 64 + cl];
    const float m = (s * (1.f / 4096.f) >= THRF) ? 1.f : 0.f;
    msA[n * 128 + c] = st[c] * m;
    mhA[n * 128 + c] = st[128 + c] * m;
}

// ---------- final: relu(bn2(y3) + x), NCHW ----------
__global__ __launch_bounds__(256) void final_k(const float* __restrict__ y3,
                                               const float* __restrict__ x,
                                               const float* __restrict__ st,
                                               float* __restrict__ out) {
    const size_t total4 = TENSOR / 4;
    for (size_t i = (size_t)blockIdx.x * 256 + threadIdx.x; i < total4;
         i += (size_t)gridDim.x * 256) {
        const int c = (int)((i >> 10) & (C_ - 1));
        const float sc = st[c], sh = st[C_ + c];
        float4 a = ((const float4*)y3)[i];
        float4 b = ((const float4*)x)[i];
        a.x = fmaxf(fmaf(a.x, sc, sh) + b.x, 0.f);
        a.y = fmaxf(fmaf(a.y, sc, sh) + b.y, 0.f);
        a.z = fmaxf(fmaf(a.z, sc, sh) + b.z, 0.f);
        a.w = fmaxf(fmaf(a.w, sc, sh) + b.w, 0.f);
        ((float4*)out)[i] = a;
    }
}

extern "C" void kernel_launch(void* const* d_in, const int* in_sizes, int n_in,
                              void* d_out, int out_size, void* d_ws, size_t ws_size,
                              hipStream_t stream) {
    const float* x  = (const float*)d_in[0];
    const float* w1 = (const float*)d_in[1];
    const float* g1 = (const float*)d_in[2];
    const float* b1 = (const float*)d_in[3];
    const float* w2 = (const float*)d_in[4];
    const float* g2 = (const float*)d_in[5];
    const float* b2 = (const float*)d_in[6];
    float* out = (float*)d_out;

    // io (padded swizzled x, 71.4MB) lives in d_out (dead until conv2 writes y3)
    unsigned short* io = (unsigned short*)d_out;

    char* wsb = (char*)d_ws;
    unsigned short* y1  = (unsigned short*)wsb;                        // 71,368,704 B
    unsigned short* Wt1 = (unsigned short*)(wsb + (size_t)71368704);   // 294,912 B
    unsigned short* Wt2 = Wt1 + 147456;                                // 294,912 B
    float* part  = (float*)(wsb + (size_t)71368704 + 589824);          // 2 MB
    float* st1   = part + 2048 * 256;
    float* st2   = st1 + 256;
    float* qsum  = st2 + 256;                                          // 128*64 floats
    float* msA   = qsum + 128 * 64;                                    // 64*128
    float* mhA   = msA + 64 * 128;                                     // 64*128

    prep_w_k<<<1152, 256, 0, stream>>>(w1, w2, Wt1, Wt2);
    zero_border_k<<<2080, 256, 0, stream>>>(io, y1);
    to_nhwc_k<<<16384, 256, 0, stream>>>(x, io);
    conv_mfma_k<1><<<2048, 256, 0, stream>>>(io, Wt1, nullptr, nullptr, y1, nullptr, part);
    bn_finalize_k<<<128, 256, 0, stream>>>(part, g1, b1, st1);
    maskpart_k<<<128, 256, 0, stream>>>(y1, st1, qsum);
    maskfin_k<<<64, 128, 0, stream>>>(qsum, st1, msA, mhA);
    conv_mfma_k<2><<<2048, 256, 0, stream>>>(y1, Wt2, msA, mhA, nullptr, out, part);
    bn_finalize_k<<<128, 256, 0, stream>>>(part, g2, b2, st2);
    final_k<<<8192, 256, 0, stream>>>(out, x, st2, out);
}